// Round 11
// baseline (126.984 us; speedup 1.0000x reference)
//
#include <hip/hip_runtime.h>

typedef __attribute__((ext_vector_type(8))) short short8;
typedef __attribute__((ext_vector_type(4))) float f32x4;
typedef unsigned short u16;
typedef unsigned int u32;
typedef unsigned char u8;
typedef __attribute__((address_space(1))) const u32 gu32;
typedef __attribute__((address_space(3))) u32 lu32;

// ---------- bf16 helpers ----------
__device__ __forceinline__ u16 f2bf(float f){
  unsigned u = __float_as_uint(f);
  u += 0x7FFF + ((u >> 16) & 1);          // round-to-nearest-even
  return (u16)(u >> 16);
}
__device__ __forceinline__ float bf2f(u16 h){ return __uint_as_float(((unsigned)h) << 16); }
// ---------- fp8 e5m2 helpers (S scores; |S| ~ 1, rel err ~6%) ----------
// pure bit-ops: rebias exp 127->15, RNE-round mantissa to 2 bits, FTZ, clamp max-finite
__device__ __forceinline__ u8 f2e5(float f){
  u32 u = __float_as_uint(f);
  u32 s = (u >> 24) & 0x80;
  int e = (int)((u >> 23) & 0xFF) - 112;        // e5 biased exponent
  u32 m = u & 0x7FFFFF;
  if (e <= 0) return (u8)s;                     // flush tiny/subnormal to zero
  if (e >= 31) return (u8)(s | 0x7B);           // clamp to max finite (e=30,m=3)
  u32 mr = m + 0xFFFFF + ((m >> 21) & 1);       // RNE at bit 21
  if (mr >> 23){ ++e; mr = 0; if (e >= 31) return (u8)(s | 0x7B); }
  return (u8)(s | ((u32)e << 2) | ((mr >> 21) & 3));
}
__device__ __forceinline__ float e52f(u8 b){
  u32 eb = (b >> 2) & 31;
  if (eb == 0) return 0.f;                      // encoded zero (FTZ at encode)
  u32 u = ((u32)(b & 0x80) << 24) | ((eb + 112) << 23) | (((u32)(b & 3)) << 21);
  return __uint_as_float(u);
}

// ---------- problem constants ----------
#define BB   16
#define NN   1024
#define DML  512
#define DL   256
#define DM   128
#define NC   10
#define SK   140
#define KTOT (NN*DM)          // 131072

// ---------- K_prep: pack weights bf16-transposed | convert W_final -> bf16 [k][c] ----------
__global__ void k_prep(const float* __restrict__ Wlin, const float* __restrict__ Wq,
                       const float* __restrict__ Wk, const float* __restrict__ Wv,
                       const float* __restrict__ Wadd,
                       u16* __restrict__ wlinT, u16* __restrict__ w4T,
                       const float* __restrict__ Wf, u16* __restrict__ wf2){
  int blk = blockIdx.x, t = threadIdx.x;
  if (blk < 512){
    int id = blk*256 + t;              // 131072
    {
      int j = id >> 9;        // 0..255  (DL)
      int k = id & 511;       // 0..511  (DML)
      wlinT[id] = f2bf(Wlin[k*DL + j]);
    }
    {
      int j = id >> 8;        // 0..511  (4*DM)
      int k = id & 255;       // 0..255  (DL)
      const float* src = (j < 128) ? Wq : (j < 256) ? Wk : (j < 384) ? Wv : Wadd;
      int jj = j & 127;
      w4T[id] = f2bf(src[k*DM + jj]);
    }
  } else {
    // W_final is already [k][c] row-major: pure f32->bf16 convert, vectorized
    int i4 = (blk-512)*256 + t;        // 327,680 float4s  (1,310,720 elems)
    float4 v = ((const float4*)Wf)[i4];
    ushort4 o; o.x=f2bf(v.x); o.y=f2bf(v.y); o.z=f2bf(v.z); o.w=f2bf(v.w);
    ((ushort4*)wf2)[i4] = o;
  }
}

// ---------- GEMM staging helpers (128-row tiles, BK=64) ----------
__device__ __forceinline__ void stage2(const u16* __restrict__ A, const u16* __restrict__ B,
                                       int K, int m0, int n0, int kb,
                                       u16* sA, u16* sB, int tid, int wave){
  #pragma unroll
  for (int i = 0; i < 4; ++i){
    int ci  = i*256 + tid;
    int row = ci >> 3;
    int kc  = (ci & 7) ^ (row & 7);
    __builtin_amdgcn_global_load_lds((gu32*)(A + (long)(m0+row)*K + kb + kc*8),
                                     (lu32*)(sA + (i*256 + wave*64)*8), 16, 0, 0);
    __builtin_amdgcn_global_load_lds((gu32*)(B + (long)(n0+row)*K + kb + kc*8),
                                     (lu32*)(sB + (i*256 + wave*64)*8), 16, 0, 0);
  }
}
// MFMA over one 64-wide K tile (128x128 tile, 4 waves of 64x64)
__device__ __forceinline__ void compute64(const u16* sA, const u16* sB,
                                          int lane, int wrow, int wcol, f32x4 acc[4][4]){
  #pragma unroll
  for (int kk = 0; kk < 2; ++kk){
    short8 af[4], bfr[4];
    int cb = kk*4 + (lane >> 4);
    #pragma unroll
    for (int m_=0; m_<4; ++m_){
      int row = wrow + m_*16 + (lane & 15);
      af[m_] = *(const short8*)&sA[row*64 + ((cb ^ (row & 7)) << 3)];
    }
    #pragma unroll
    for (int n_=0; n_<4; ++n_){
      int row = wcol + n_*16 + (lane & 15);
      bfr[n_] = *(const short8*)&sB[row*64 + ((cb ^ (row & 7)) << 3)];
    }
    #pragma unroll
    for (int m_=0; m_<4; ++m_)
      #pragma unroll
      for (int n_=0; n_<4; ++n_)
        acc[m_][n_] = __builtin_amdgcn_mfma_f32_16x16x32_bf16(af[m_], bfr[n_], acc[m_][n_], 0, 0, 0);
  }
}
// double-buffered core: 1 barrier per K-step, stage(next) overlaps compute(cur)
__device__ __forceinline__ void gemm_core_db(const u16* __restrict__ A, const u16* __restrict__ B,
                                             int K, int m0, int n0,
                                             u16* sA0, u16* sB0, u16* sA1, u16* sB1,
                                             f32x4 acc[4][4]){
  const int tid  = threadIdx.x;
  const int lane = tid & 63;
  const int wave = tid >> 6;
  const int wrow = (wave >> 1) * 64;
  const int wcol = (wave & 1) * 64;
  u16 *cA = sA0, *cB = sB0, *nA = sA1, *nB = sB1;
  stage2(A, B, K, m0, n0, 0, cA, cB, tid, wave);
  __syncthreads();
  int nt = K >> 6;
  for (int t = 0; t < nt-1; ++t){
    stage2(A, B, K, m0, n0, (t+1)*64, nA, nB, tid, wave);
    compute64(cA, cB, lane, wrow, wcol, acc);
    __syncthreads();
    u16* x;
    x = cA; cA = nA; nA = x;
    x = cB; cB = nB; nB = x;
  }
  compute64(cA, cB, lane, wrow, wcol, acc);
}

// ---------- K2: x = emb(f32) @ W_lin + b_lin -> bf16 ; BM=64 x BN=128, 2 blocks-deep N-split ----------
__global__ __launch_bounds__(256) void k_gemm_x(const float* __restrict__ A, const u16* __restrict__ B,
                                                const float* __restrict__ bias, u16* __restrict__ out){
  __shared__ u16 sA[64*64];     // 8KB
  __shared__ u16 sB[128*64];    // 16KB
  const int tid  = threadIdx.x;
  const int lane = tid & 63;
  const int wave = tid >> 6;
  const int wrow = (wave >> 1) * 32;
  const int wcol = (wave & 1) * 64;
  int m0 = blockIdx.x*64, n0 = blockIdx.y*128;
  f32x4 acc[2][4];
  f32x4 z = {0.f,0.f,0.f,0.f};
  #pragma unroll
  for (int m_=0;m_<2;++m_) for (int n_=0;n_<4;++n_) acc[m_][n_] = z;

  f32x4 ra[4];      // A: 16 f32 per thread (row = tid>>2, two chunks kc=aq*2, aq*2+1)
  short8 rb[4];     // B: 4 chunks per thread
  const int arow = tid >> 2, aq = tid & 3;

  // prologue: tile 0
  {
    const float* src = A + (long)(m0+arow)*DML + aq*16;
    ra[0] = ((const f32x4*)src)[0]; ra[1] = ((const f32x4*)src)[1];
    ra[2] = ((const f32x4*)src)[2]; ra[3] = ((const f32x4*)src)[3];
    #pragma unroll
    for (int i=0;i<4;++i){
      int ci = i*256 + tid, row = ci>>3, kc = ci&7;
      rb[i] = *(const short8*)(B + (long)(n0+row)*DML + kc*8);
    }
  }
  {
    short8 o0, o1;
    #pragma unroll
    for (int j=0;j<4;++j){ o0[j]=(short)f2bf(ra[0][j]); o0[4+j]=(short)f2bf(ra[1][j]);
                           o1[j]=(short)f2bf(ra[2][j]); o1[4+j]=(short)f2bf(ra[3][j]); }
    int kc0 = aq*2, kc1 = aq*2+1;
    *(short8*)&sA[arow*64 + ((kc0 ^ (arow&7))<<3)] = o0;
    *(short8*)&sA[arow*64 + ((kc1 ^ (arow&7))<<3)] = o1;
    #pragma unroll
    for (int i=0;i<4;++i){
      int ci = i*256 + tid, row = ci>>3, kc = ci&7;
      *(short8*)&sB[row*64 + ((kc ^ (row&7))<<3)] = rb[i];
    }
  }
  __syncthreads();

  for (int tt = 0; tt < 8; ++tt){
    if (tt < 7){
      int kb = (tt+1)*64;
      const float* src = A + (long)(m0+arow)*DML + kb + aq*16;
      ra[0] = ((const f32x4*)src)[0]; ra[1] = ((const f32x4*)src)[1];
      ra[2] = ((const f32x4*)src)[2]; ra[3] = ((const f32x4*)src)[3];
      #pragma unroll
      for (int i=0;i<4;++i){
        int ci = i*256 + tid, row = ci>>3, kc = ci&7;
        rb[i] = *(const short8*)(B + (long)(n0+row)*DML + kb + kc*8);
      }
    }
    #pragma unroll
    for (int kk = 0; kk < 2; ++kk){
      short8 af[2], bfr[4];
      int cb = kk*4 + (lane >> 4);
      #pragma unroll
      for (int m_=0; m_<2; ++m_){
        int row = wrow + m_*16 + (lane & 15);
        af[m_] = *(const short8*)&sA[row*64 + ((cb ^ (row & 7)) << 3)];
      }
      #pragma unroll
      for (int n_=0; n_<4; ++n_){
        int row = wcol + n_*16 + (lane & 15);
        bfr[n_] = *(const short8*)&sB[row*64 + ((cb ^ (row & 7)) << 3)];
      }
      #pragma unroll
      for (int m_=0; m_<2; ++m_)
        #pragma unroll
        for (int n_=0; n_<4; ++n_)
          acc[m_][n_] = __builtin_amdgcn_mfma_f32_16x16x32_bf16(af[m_], bfr[n_], acc[m_][n_], 0, 0, 0);
    }
    __syncthreads();
    if (tt < 7){
      short8 o0, o1;
      #pragma unroll
      for (int j=0;j<4;++j){ o0[j]=(short)f2bf(ra[0][j]); o0[4+j]=(short)f2bf(ra[1][j]);
                             o1[j]=(short)f2bf(ra[2][j]); o1[4+j]=(short)f2bf(ra[3][j]); }
      int kc0 = aq*2, kc1 = aq*2+1;
      *(short8*)&sA[arow*64 + ((kc0 ^ (arow&7))<<3)] = o0;
      *(short8*)&sA[arow*64 + ((kc1 ^ (arow&7))<<3)] = o1;
      #pragma unroll
      for (int i=0;i<4;++i){
        int ci = i*256 + tid, row = ci>>3, kc = ci&7;
        *(short8*)&sB[row*64 + ((kc ^ (row&7))<<3)] = rb[i];
      }
      __syncthreads();
    }
  }

  #pragma unroll
  for (int m_=0;m_<2;++m_)
    #pragma unroll
    for (int n_=0;n_<4;++n_)
      #pragma unroll
      for (int rr=0;rr<4;++rr){
        int row = m0 + wrow + m_*16 + (lane>>4)*4 + rr;
        int col = n0 + wcol + n_*16 + (lane & 15);
        out[(long)row*DL + col] = f2bf(acc[m_][n_][rr] + bias[col]);
      }
}

// ---------- K3: [Q|K|V|A] = x @ [Wq|Wk|Wv|Wadd] ----------
__global__ __launch_bounds__(256) void k_gemm_qkva(const u16* __restrict__ A, const u16* __restrict__ B,
                                                   const float* __restrict__ badd,
                                                   u16* __restrict__ oq, u16* __restrict__ ok,
                                                   u16* __restrict__ ov, u16* __restrict__ oa){
  __shared__ u16 sA0[128*64], sB0[128*64], sA1[128*64], sB1[128*64];
  f32x4 acc[4][4];
  f32x4 z = {0.f,0.f,0.f,0.f};
  #pragma unroll
  for (int m_=0;m_<4;++m_) for (int n_=0;n_<4;++n_) acc[m_][n_] = z;
  int m0 = blockIdx.x*128;
  int tn = blockIdx.y;              // 0=Q 1=K 2=V 3=A
  gemm_core_db(A, B, DL, m0, tn*128, sA0, sB0, sA1, sB1, acc);
  int lane = threadIdx.x & 63, wave = threadIdx.x >> 6;
  int wrow = (wave>>1)*64, wcol = (wave&1)*64;
  u16* dst = (tn==0) ? oq : (tn==1) ? ok : (tn==2) ? ov : oa;
  #pragma unroll
  for (int m_=0;m_<4;++m_)
    #pragma unroll
    for (int n_=0;n_<4;++n_)
      #pragma unroll
      for (int r=0;r<4;++r){
        int row = m0 + wrow + m_*16 + (lane>>4)*4 + r;
        int cl  = (wcol + n_*16 + (lane & 15)) & 127;
        float v = acc[m_][n_][r];
        if (tn == 3) v += badd[cl];
        dst[(long)row*DM + cl] = f2bf(v);
      }
}

// ---------- K4: S[b] = Q[b] @ K[b]^T -> fp8 e5m2 ----------
__global__ __launch_bounds__(256) void k_gemm_s(const u16* __restrict__ Q, const u16* __restrict__ Km,
                                                u8* __restrict__ S){
  __shared__ u16 sA0[128*64], sB0[128*64], sA1[128*64], sB1[128*64];
  f32x4 acc[4][4];
  f32x4 z = {0.f,0.f,0.f,0.f};
  #pragma unroll
  for (int m_=0;m_<4;++m_) for (int n_=0;n_<4;++n_) acc[m_][n_] = z;
  int b  = blockIdx.z;
  int m0 = blockIdx.x*128, n0 = blockIdx.y*128;
  const u16* A = Q  + (long)b*NN*DM;
  const u16* B = Km + (long)b*NN*DM;
  gemm_core_db(A, B, DM, m0, n0, sA0, sB0, sA1, sB1, acc);
  int lane = threadIdx.x & 63, wave = threadIdx.x >> 6;
  int wrow = (wave>>1)*64, wcol = (wave&1)*64;
  u8* Sb = S + (long)b*NN*NN;
  #pragma unroll
  for (int m_=0;m_<4;++m_)
    #pragma unroll
    for (int n_=0;n_<4;++n_)
      #pragma unroll
      for (int r=0;r<4;++r){
        int row = m0 + wrow + m_*16 + (lane>>4)*4 + r;
        int col = n0 + wcol + n_*16 + (lane & 15);
        Sb[(long)row*NN + col] = f2e5(acc[m_][n_][r]);
      }
}

// ---------- K5: M[b,l] = max_s S[b,l,idx[l,s]] - sum_s(...)/1024 ----------
__global__ void k_mscore(const u8* __restrict__ S, const int* __restrict__ idx, float* __restrict__ M){
  int g    = blockIdx.x*4 + (threadIdx.x >> 6);   // one wave per (b,l)
  int lane = threadIdx.x & 63;
  int b = g >> 10, l = g & 1023;
  const u8* Srow = S + (long)b*NN*NN + (long)l*NN;
  const int* ir = idx + l*SK;
  float mx = -1e30f, sm = 0.f;
  for (int s = lane; s < SK; s += 64){
    float v = e52f(Srow[ir[s]]);
    mx = fmaxf(mx, v); sm += v;
  }
  #pragma unroll
  for (int o=32;o;o>>=1){ mx = fmaxf(mx, __shfl_xor(mx,o)); sm += __shfl_xor(sm,o); }
  if (lane == 0) M[g] = mx - sm * (1.0f/1024.0f);
}

// ---------- K6a: partial ranks (blocks 0..255) + V column-mean (blocks 256..271) ----------
__global__ __launch_bounds__(256) void k_rankvm(const float* __restrict__ M, int* __restrict__ partial,
                                                const u16* __restrict__ V, float* __restrict__ vmean){
  __shared__ float sC[64];
  __shared__ float red[16][128];
  int blk = blockIdx.x, t = threadIdx.x;
  if (blk < 256){
    int jc = blk & 15, b = blk >> 4;
    const float* Mb = M + b*NN;
    if (t < 64) sC[t] = Mb[jc*64 + t];
    __syncthreads();
    int j0 = jc*64;
    float mi[4];
    int cnt[4] = {0,0,0,0};
    #pragma unroll
    for (int r=0;r<4;++r) mi[r] = Mb[t + r*256];
    for (int j = 0; j < 64; ++j){
      float mj = sC[j];
      int jg = j0 + j;
      #pragma unroll
      for (int r=0;r<4;++r){
        int i = t + r*256;
        cnt[r] += (mj > mi[r]) || (mj == mi[r] && jg < i);
      }
    }
    int* pb = partial + (b*16 + jc)*NN;
    #pragma unroll
    for (int r=0;r<4;++r) pb[t + r*256] = cnt[r];
  } else {
    int b = blk - 256;
    int d8 = t & 15, seg = t >> 4;
    const u16* Vb = V + (long)b*KTOT + seg*64*DM + d8*8;
    float acc[8] = {0,0,0,0,0,0,0,0};
    for (int l = 0; l < 64; ++l){
      short8 v = *(const short8*)(Vb + l*DM);
      #pragma unroll
      for (int j=0;j<8;++j) acc[j] += bf2f((u16)v[j]);
    }
    #pragma unroll
    for (int j=0;j<8;++j) red[seg][d8*8+j] = acc[j];
    __syncthreads();
    if (t < 128){
      float s = 0.f;
      #pragma unroll
      for (int g=0;g<16;++g) s += red[g][t];
      vmean[b*DM + t] = s * (1.0f/1024.0f);
    }
  }
}

// ---------- K6b: sum partial ranks -> mtop + selmap ----------
__global__ __launch_bounds__(1024) void k_sel(const int* __restrict__ partial, int* __restrict__ mtop,
                                              int* __restrict__ selmap){
  int b = blockIdx.x, i = threadIdx.x;
  int cnt = 0;
  #pragma unroll
  for (int jc = 0; jc < 16; ++jc) cnt += partial[(b*16 + jc)*NN + i];
  selmap[b*NN + i] = (cnt < SK) ? cnt : -1;
  if (cnt < SK) mtop[b*SK + cnt] = i;
}

// ---------- K9: softmax(S_row/sqrt(d)) @ V for top-140 rows, 4 rows/block ----------
// PV: dg = t&15 (coalesced V loads), kg = t>>4; reduce shfl(16,32) + LDS cross-wave.
__global__ __launch_bounds__(256) void k_attn(const u8* __restrict__ S, const u16* __restrict__ V,
                                              const int* __restrict__ mtop, float* __restrict__ upd){
  __shared__ float sE[4][1024];
  __shared__ float redM[4][4];
  __shared__ float redS[4][4];
  __shared__ float sP[4][4][128];   // [wave][row][d] 8KB
  int b = blockIdx.y, u0 = blockIdx.x*4, t = threadIdx.x;
  int lane = t & 63, wave = t >> 6;
  const float inv = 0.08838834764831845f;   // 1/sqrt(128)

  int rows[4];
  #pragma unroll
  for (int r=0;r<4;++r) rows[r] = mtop[b*SK + u0 + r];

  float sv[4][4];
  float pm[4];
  const u8* Sb = S + (long)b*NN*NN;
  #pragma unroll
  for (int r=0;r<4;++r){
    uchar4 raw = ((const uchar4*)(Sb + (long)rows[r]*NN))[t];
    sv[r][0] = e52f(raw.x)*inv; sv[r][1] = e52f(raw.y)*inv;
    sv[r][2] = e52f(raw.z)*inv; sv[r][3] = e52f(raw.w)*inv;
    pm[r] = fmaxf(fmaxf(sv[r][0],sv[r][1]), fmaxf(sv[r][2],sv[r][3]));
  }
  #pragma unroll
  for (int o=32;o;o>>=1)
    #pragma unroll
    for (int r=0;r<4;++r) pm[r] = fmaxf(pm[r], __shfl_xor(pm[r],o));
  if (lane == 0){
    #pragma unroll
    for (int r=0;r<4;++r) redM[wave][r] = pm[r];
  }
  __syncthreads();
  float mx[4], ps[4];
  #pragma unroll
  for (int r=0;r<4;++r)
    mx[r] = fmaxf(fmaxf(redM[0][r],redM[1][r]), fmaxf(redM[2][r],redM[3][r]));
  #pragma unroll
  for (int r=0;r<4;++r){
    float s = 0.f;
    #pragma unroll
    for (int j=0;j<4;++j){
      float e = __expf(sv[r][j] - mx[r]);
      sE[r][t*4+j] = e;
      s += e;
    }
    ps[r] = s;
  }
  #pragma unroll
  for (int o=32;o;o>>=1)
    #pragma unroll
    for (int r=0;r<4;++r) ps[r] += __shfl_xor(ps[r],o);
  if (lane == 0){
    #pragma unroll
    for (int r=0;r<4;++r) redS[wave][r] = ps[r];
  }
  __syncthreads();
  float rZ[4];
  #pragma unroll
  for (int r=0;r<4;++r)
    rZ[r] = 1.0f / (redS[0][r]+redS[1][r]+redS[2][r]+redS[3][r]);

  // ---- PV, coalesced: dg = t&15, kg = t>>4 ----
  int dg = t & 15;
  int kg = t >> 4;
  const u16* Vb = V + (long)b*KTOT + dg*8;
  float acc[4][8];
  #pragma unroll
  for (int r=0;r<4;++r)
    #pragma unroll
    for (int j=0;j<8;++j) acc[r][j] = 0.f;

  for (int k = kg; k < NN; k += 16){
    short8 v = *(const short8*)(Vb + (long)k*DM);
    float vf[8];
    #pragma unroll
    for (int j=0;j<8;++j) vf[j] = bf2f((u16)v[j]);
    #pragma unroll
    for (int r=0;r<4;++r){
      float e = sE[r][k];
      #pragma unroll
      for (int j=0;j<8;++j) acc[r][j] += e * vf[j];
    }
  }

  // reduce over this wave's 4 kg values (lane bits 4,5)
  #pragma unroll
  for (int o=16;o<64;o<<=1)
    #pragma unroll
    for (int r=0;r<4;++r)
      #pragma unroll
      for (int j=0;j<8;++j) acc[r][j] += __shfl_xor(acc[r][j], o);

  if ((t & 63) < 16){
    #pragma unroll
    for (int r=0;r<4;++r)
      #pragma unroll
      for (int j=0;j<8;++j) sP[wave][r][dg*8+j] = acc[r][j];
  }
  __syncthreads();
  if (t < 128){
    #pragma unroll
    for (int r=0;r<4;++r){
      float s = sP[0][r][t] + sP[1][r][t] + sP[2][r][t] + sP[3][r][t];
      upd[((long)b*SK + u0 + r)*DM + t] = s * rZ[r];
    }
  }
}

// ---------- K11: final GEMV partials: (ctx+A) @ W_final ; wf2 is [k][c] contiguous ----------
__global__ __launch_bounds__(256) void k_final(const float* __restrict__ upd, const float* __restrict__ vmean,
                                               const int* __restrict__ selmap,
                                               const u16* __restrict__ Aad,
                                               const u16* __restrict__ wf2, float* __restrict__ part){
  int b = blockIdx.x, ch = blockIdx.y, t = threadIdx.x;
  long base = (long)b * KTOT;
  int k0 = ch * 4096;
  float acc[NC] = {0.f};
  for (int k = k0 + t; k < k0 + 4096; k += 256){
    int l = k >> 7, d = k & 127;
    int sel = selmap[b*NN + l];
    float c = (sel >= 0) ? upd[((long)b*SK + sel)*DM + d] : vmean[b*DM + d];
    float v = c + bf2f(Aad[base + k]);
    const u32* w32 = (const u32*)(wf2 + (long)k*NC);   // 10 bf16 = 20B contiguous
    #pragma unroll
    for (int cc = 0; cc < 5; ++cc){
      u32 w = w32[cc];
      acc[2*cc]   += v * bf2f((u16)(w & 0xFFFF));
      acc[2*cc+1] += v * bf2f((u16)(w >> 16));
    }
  }
  __shared__ float lred[40];
  int lane = t & 63, wave = t >> 6;
  #pragma unroll
  for (int c = 0; c < NC; ++c){
    float v = acc[c];
    #pragma unroll
    for (int o=32;o;o>>=1) v += __shfl_xor(v,o);
    if (lane == 0) lred[wave*NC + c] = v;
  }
  __syncthreads();
  if (t < NC) part[(b*32 + ch)*NC + t] = lred[t] + lred[NC+t] + lred[2*NC+t] + lred[3*NC+t];
}

// ---------- K12: reduce partials + bias -> out ----------
__global__ void k_out(const float* __restrict__ part, const float* __restrict__ bfin, float* __restrict__ out){
  int t = threadIdx.x;
  if (t < BB*NC){
    int b = t / NC, c = t % NC;
    float s = bfin[c];
    #pragma unroll
    for (int ch = 0; ch < 32; ++ch) s += part[(b*32 + ch)*NC + c];
    out[t] = s;
  }
}

// ---------- launch ----------
extern "C" void kernel_launch(void* const* d_in, const int* in_sizes, int n_in,
                              void* d_out, int out_size, void* d_ws, size_t ws_size,
                              hipStream_t stream){
  const float* emb  = (const float*)d_in[0];
  const int*   idxs = (const int*)  d_in[1];
  const float* Wlin = (const float*)d_in[2];
  const float* blin = (const float*)d_in[3];
  const float* Wq   = (const float*)d_in[4];
  const float* Wk   = (const float*)d_in[5];
  const float* Wv   = (const float*)d_in[6];
  const float* Wadd = (const float*)d_in[7];
  const float* badd = (const float*)d_in[8];
  const float* Wfin = (const float*)d_in[9];
  const float* bfin = (const float*)d_in[10];
  float* out = (float*)d_out;

  char* p = (char*)d_ws;
  auto alloc = [&](size_t bytes)->char*{ char* r = p; p += (bytes + 255) & ~(size_t)255; return r; };
  u16*   wlinT  = (u16*)  alloc((size_t)DL*DML*2);
  u16*   w4T    = (u16*)  alloc((size_t)4*DM*DL*2);
  u16*   x_bf   = (u16*)  alloc((size_t)BB*NN*DL*2);
  u16*   q_bf   = (u16*)  alloc((size_t)BB*NN*DM*2);
  u16*   k_bf   = (u16*)  alloc((size_t)BB*NN*DM*2);
  u16*   v_bf   = (u16*)  alloc((size_t)BB*NN*DM*2);
  u16*   a_bf   = (u16*)  alloc((size_t)BB*NN*DM*2);
  u8*    s_f8   = (u8*)   alloc((size_t)BB*NN*NN);
  float* m_f    = (float*)alloc((size_t)BB*NN*4);
  int*   rankp  = (int*)  alloc((size_t)BB*16*NN*4);
  int*   mtop   = (int*)  alloc((size_t)BB*SK*4);
  int*   selmap = (int*)  alloc((size_t)BB*NN*4);
  float* vmean  = (float*)alloc((size_t)BB*DM*4);
  float* upd    = (float*)alloc((size_t)BB*SK*DM*4);
  u16*   wf2    = (u16*)  alloc((size_t)KTOT*NC*2);
  float* part   = (float*)alloc((size_t)BB*32*NC*4);

  // 1: pack weights + wf2 (no transpose)
  k_prep<<<dim3(1792), dim3(256), 0, stream>>>(Wlin, Wq, Wk, Wv, Wadd, wlinT, w4T, Wfin, wf2);
  // 2: x = emb @ Wlin + b  (BN=128 split for 2x occupancy)
  k_gemm_x<<<dim3(256, 2), dim3(256), 0, stream>>>(emb, wlinT, blin, x_bf);
  // 3: Q,K,V,A
  k_gemm_qkva<<<dim3(128, 4), dim3(256), 0, stream>>>(x_bf, w4T, badd, q_bf, k_bf, v_bf, a_bf);
  // 4: S = Q K^T per batch -> fp8 e5m2
  k_gemm_s<<<dim3(8, 8, 16), dim3(256), 0, stream>>>(q_bf, k_bf, s_f8);
  // 5: M scores
  k_mscore<<<dim3(BB*NN/4), dim3(256), 0, stream>>>(s_f8, idxs, m_f);
  // 6: partial ranks + vmean
  k_rankvm<<<dim3(272), dim3(256), 0, stream>>>(m_f, rankp, v_bf, vmean);
  // 7: select top-140
  k_sel<<<dim3(BB), dim3(1024), 0, stream>>>(rankp, mtop, selmap);
  // 8: attention rows -> compact upd (coalesced PV)
  k_attn<<<dim3(SK/4, BB), dim3(256), 0, stream>>>(s_f8, v_bf, mtop, upd);
  // 9/10: final projection
  k_final<<<dim3(BB, 32), dim3(256), 0, stream>>>(upd, vmean, selmap, a_bf, wf2, part);
  k_out<<<dim3(1), dim3(256), 0, stream>>>(part, bfin, out);
}

// Round 12
// 115.839 us; speedup vs baseline: 1.0962x; 1.0962x over previous
//
#include <hip/hip_runtime.h>

typedef __attribute__((ext_vector_type(8))) short short8;
typedef __attribute__((ext_vector_type(4))) float f32x4;
typedef unsigned short u16;
typedef unsigned int u32;
typedef __attribute__((address_space(1))) const u32 gu32;
typedef __attribute__((address_space(3))) u32 lu32;

// ---------- bf16 helpers ----------
__device__ __forceinline__ u16 f2bf(float f){
  unsigned u = __float_as_uint(f);
  u += 0x7FFF + ((u >> 16) & 1);          // round-to-nearest-even
  return (u16)(u >> 16);
}
__device__ __forceinline__ float bf2f(u16 h){ return __uint_as_float(((unsigned)h) << 16); }

// ---------- problem constants ----------
#define BB   16
#define NN   1024
#define DML  512
#define DL   256
#define DM   128
#define NC   10
#define SK   140
#define KTOT (NN*DM)          // 131072

// ---------- K_prep: pack weights bf16-transposed | convert W_final -> bf16 [k][c] ----------
__global__ void k_prep(const float* __restrict__ Wlin, const float* __restrict__ Wq,
                       const float* __restrict__ Wk, const float* __restrict__ Wv,
                       const float* __restrict__ Wadd,
                       u16* __restrict__ wlinT, u16* __restrict__ w4T,
                       const float* __restrict__ Wf, u16* __restrict__ wf2){
  int blk = blockIdx.x, t = threadIdx.x;
  if (blk < 512){
    int id = blk*256 + t;              // 131072
    {
      int j = id >> 9;        // 0..255  (DL)
      int k = id & 511;       // 0..511  (DML)
      wlinT[id] = f2bf(Wlin[k*DL + j]);
    }
    {
      int j = id >> 8;        // 0..511  (4*DM)
      int k = id & 255;       // 0..255  (DL)
      const float* src = (j < 128) ? Wq : (j < 256) ? Wk : (j < 384) ? Wv : Wadd;
      int jj = j & 127;
      w4T[id] = f2bf(src[k*DM + jj]);
    }
  } else {
    // W_final is already [k][c] row-major: pure f32->bf16 convert, vectorized
    int i4 = (blk-512)*256 + t;        // 327,680 float4s  (1,310,720 elems)
    float4 v = ((const float4*)Wf)[i4];
    ushort4 o; o.x=f2bf(v.x); o.y=f2bf(v.y); o.z=f2bf(v.z); o.w=f2bf(v.w);
    ((ushort4*)wf2)[i4] = o;
  }
}

// ---------- GEMM staging helpers (128-row tiles, BK=64) ----------
__device__ __forceinline__ void stage2(const u16* __restrict__ A, const u16* __restrict__ B,
                                       int K, int m0, int n0, int kb,
                                       u16* sA, u16* sB, int tid, int wave){
  #pragma unroll
  for (int i = 0; i < 4; ++i){
    int ci  = i*256 + tid;
    int row = ci >> 3;
    int kc  = (ci & 7) ^ (row & 7);
    __builtin_amdgcn_global_load_lds((gu32*)(A + (long)(m0+row)*K + kb + kc*8),
                                     (lu32*)(sA + (i*256 + wave*64)*8), 16, 0, 0);
    __builtin_amdgcn_global_load_lds((gu32*)(B + (long)(n0+row)*K + kb + kc*8),
                                     (lu32*)(sB + (i*256 + wave*64)*8), 16, 0, 0);
  }
}
// MFMA over one 64-wide K tile (128x128 tile, 4 waves of 64x64)
__device__ __forceinline__ void compute64(const u16* sA, const u16* sB,
                                          int lane, int wrow, int wcol, f32x4 acc[4][4]){
  #pragma unroll
  for (int kk = 0; kk < 2; ++kk){
    short8 af[4], bfr[4];
    int cb = kk*4 + (lane >> 4);
    #pragma unroll
    for (int m_=0; m_<4; ++m_){
      int row = wrow + m_*16 + (lane & 15);
      af[m_] = *(const short8*)&sA[row*64 + ((cb ^ (row & 7)) << 3)];
    }
    #pragma unroll
    for (int n_=0; n_<4; ++n_){
      int row = wcol + n_*16 + (lane & 15);
      bfr[n_] = *(const short8*)&sB[row*64 + ((cb ^ (row & 7)) << 3)];
    }
    #pragma unroll
    for (int m_=0; m_<4; ++m_)
      #pragma unroll
      for (int n_=0; n_<4; ++n_)
        acc[m_][n_] = __builtin_amdgcn_mfma_f32_16x16x32_bf16(af[m_], bfr[n_], acc[m_][n_], 0, 0, 0);
  }
}
// double-buffered core: 1 barrier per K-step, stage(next) overlaps compute(cur)
__device__ __forceinline__ void gemm_core_db(const u16* __restrict__ A, const u16* __restrict__ B,
                                             int K, int m0, int n0,
                                             u16* sA0, u16* sB0, u16* sA1, u16* sB1,
                                             f32x4 acc[4][4]){
  const int tid  = threadIdx.x;
  const int lane = tid & 63;
  const int wave = tid >> 6;
  const int wrow = (wave >> 1) * 64;
  const int wcol = (wave & 1) * 64;
  u16 *cA = sA0, *cB = sB0, *nA = sA1, *nB = sB1;
  stage2(A, B, K, m0, n0, 0, cA, cB, tid, wave);
  __syncthreads();
  int nt = K >> 6;
  for (int t = 0; t < nt-1; ++t){
    stage2(A, B, K, m0, n0, (t+1)*64, nA, nB, tid, wave);
    compute64(cA, cB, lane, wrow, wcol, acc);
    __syncthreads();
    u16* x;
    x = cA; cA = nA; nA = x;
    x = cB; cB = nB; nB = x;
  }
  compute64(cA, cB, lane, wrow, wcol, acc);
}

// ---------- K2: x = emb(f32) @ W_lin + b_lin -> bf16 ; BM=64 x BN=128, 2 blocks-deep N-split ----------
__global__ __launch_bounds__(256) void k_gemm_x(const float* __restrict__ A, const u16* __restrict__ B,
                                                const float* __restrict__ bias, u16* __restrict__ out){
  __shared__ u16 sA[64*64];     // 8KB
  __shared__ u16 sB[128*64];    // 16KB
  const int tid  = threadIdx.x;
  const int lane = tid & 63;
  const int wave = tid >> 6;
  const int wrow = (wave >> 1) * 32;
  const int wcol = (wave & 1) * 64;
  int m0 = blockIdx.x*64, n0 = blockIdx.y*128;
  f32x4 acc[2][4];
  f32x4 z = {0.f,0.f,0.f,0.f};
  #pragma unroll
  for (int m_=0;m_<2;++m_) for (int n_=0;n_<4;++n_) acc[m_][n_] = z;

  f32x4 ra[4];      // A: 16 f32 per thread (row = tid>>2, two chunks kc=aq*2, aq*2+1)
  short8 rb[4];     // B: 4 chunks per thread
  const int arow = tid >> 2, aq = tid & 3;

  // prologue: tile 0
  {
    const float* src = A + (long)(m0+arow)*DML + aq*16;
    ra[0] = ((const f32x4*)src)[0]; ra[1] = ((const f32x4*)src)[1];
    ra[2] = ((const f32x4*)src)[2]; ra[3] = ((const f32x4*)src)[3];
    #pragma unroll
    for (int i=0;i<4;++i){
      int ci = i*256 + tid, row = ci>>3, kc = ci&7;
      rb[i] = *(const short8*)(B + (long)(n0+row)*DML + kc*8);
    }
  }
  {
    short8 o0, o1;
    #pragma unroll
    for (int j=0;j<4;++j){ o0[j]=(short)f2bf(ra[0][j]); o0[4+j]=(short)f2bf(ra[1][j]);
                           o1[j]=(short)f2bf(ra[2][j]); o1[4+j]=(short)f2bf(ra[3][j]); }
    int kc0 = aq*2, kc1 = aq*2+1;
    *(short8*)&sA[arow*64 + ((kc0 ^ (arow&7))<<3)] = o0;
    *(short8*)&sA[arow*64 + ((kc1 ^ (arow&7))<<3)] = o1;
    #pragma unroll
    for (int i=0;i<4;++i){
      int ci = i*256 + tid, row = ci>>3, kc = ci&7;
      *(short8*)&sB[row*64 + ((kc ^ (row&7))<<3)] = rb[i];
    }
  }
  __syncthreads();

  for (int tt = 0; tt < 8; ++tt){
    if (tt < 7){
      int kb = (tt+1)*64;
      const float* src = A + (long)(m0+arow)*DML + kb + aq*16;
      ra[0] = ((const f32x4*)src)[0]; ra[1] = ((const f32x4*)src)[1];
      ra[2] = ((const f32x4*)src)[2]; ra[3] = ((const f32x4*)src)[3];
      #pragma unroll
      for (int i=0;i<4;++i){
        int ci = i*256 + tid, row = ci>>3, kc = ci&7;
        rb[i] = *(const short8*)(B + (long)(n0+row)*DML + kb + kc*8);
      }
    }
    #pragma unroll
    for (int kk = 0; kk < 2; ++kk){
      short8 af[2], bfr[4];
      int cb = kk*4 + (lane >> 4);
      #pragma unroll
      for (int m_=0; m_<2; ++m_){
        int row = wrow + m_*16 + (lane & 15);
        af[m_] = *(const short8*)&sA[row*64 + ((cb ^ (row & 7)) << 3)];
      }
      #pragma unroll
      for (int n_=0; n_<4; ++n_){
        int row = wcol + n_*16 + (lane & 15);
        bfr[n_] = *(const short8*)&sB[row*64 + ((cb ^ (row & 7)) << 3)];
      }
      #pragma unroll
      for (int m_=0; m_<2; ++m_)
        #pragma unroll
        for (int n_=0; n_<4; ++n_)
          acc[m_][n_] = __builtin_amdgcn_mfma_f32_16x16x32_bf16(af[m_], bfr[n_], acc[m_][n_], 0, 0, 0);
    }
    __syncthreads();
    if (tt < 7){
      short8 o0, o1;
      #pragma unroll
      for (int j=0;j<4;++j){ o0[j]=(short)f2bf(ra[0][j]); o0[4+j]=(short)f2bf(ra[1][j]);
                             o1[j]=(short)f2bf(ra[2][j]); o1[4+j]=(short)f2bf(ra[3][j]); }
      int kc0 = aq*2, kc1 = aq*2+1;
      *(short8*)&sA[arow*64 + ((kc0 ^ (arow&7))<<3)] = o0;
      *(short8*)&sA[arow*64 + ((kc1 ^ (arow&7))<<3)] = o1;
      #pragma unroll
      for (int i=0;i<4;++i){
        int ci = i*256 + tid, row = ci>>3, kc = ci&7;
        *(short8*)&sB[row*64 + ((kc ^ (row&7))<<3)] = rb[i];
      }
      __syncthreads();
    }
  }

  #pragma unroll
  for (int m_=0;m_<2;++m_)
    #pragma unroll
    for (int n_=0;n_<4;++n_)
      #pragma unroll
      for (int rr=0;rr<4;++rr){
        int row = m0 + wrow + m_*16 + (lane>>4)*4 + rr;
        int col = n0 + wcol + n_*16 + (lane & 15);
        out[(long)row*DL + col] = f2bf(acc[m_][n_][rr] + bias[col]);
      }
}

// ---------- K3: [Q|K|V|A] = x @ [Wq|Wk|Wv|Wadd] ----------
__global__ __launch_bounds__(256) void k_gemm_qkva(const u16* __restrict__ A, const u16* __restrict__ B,
                                                   const float* __restrict__ badd,
                                                   u16* __restrict__ oq, u16* __restrict__ ok,
                                                   u16* __restrict__ ov, u16* __restrict__ oa){
  __shared__ u16 sA0[128*64], sB0[128*64], sA1[128*64], sB1[128*64];
  f32x4 acc[4][4];
  f32x4 z = {0.f,0.f,0.f,0.f};
  #pragma unroll
  for (int m_=0;m_<4;++m_) for (int n_=0;n_<4;++n_) acc[m_][n_] = z;
  int m0 = blockIdx.x*128;
  int tn = blockIdx.y;              // 0=Q 1=K 2=V 3=A
  gemm_core_db(A, B, DL, m0, tn*128, sA0, sB0, sA1, sB1, acc);
  int lane = threadIdx.x & 63, wave = threadIdx.x >> 6;
  int wrow = (wave>>1)*64, wcol = (wave&1)*64;
  u16* dst = (tn==0) ? oq : (tn==1) ? ok : (tn==2) ? ov : oa;
  #pragma unroll
  for (int m_=0;m_<4;++m_)
    #pragma unroll
    for (int n_=0;n_<4;++n_)
      #pragma unroll
      for (int r=0;r<4;++r){
        int row = m0 + wrow + m_*16 + (lane>>4)*4 + r;
        int cl  = (wcol + n_*16 + (lane & 15)) & 127;
        float v = acc[m_][n_][r];
        if (tn == 3) v += badd[cl];
        dst[(long)row*DM + cl] = f2bf(v);
      }
}

// ---------- K4: S[b] = Q[b] @ K[b]^T -> bf16, LDS-staged COALESCED epilogue ----------
__global__ __launch_bounds__(256) void k_gemm_s(const u16* __restrict__ Q, const u16* __restrict__ Km,
                                                u16* __restrict__ S){
  __shared__ u16 smem[32768];     // 64KB: 4x8192 staging; first 16384 reused for C tile
  u16* sA0 = smem;
  u16* sB0 = smem + 8192;
  u16* sA1 = smem + 16384;
  u16* sB1 = smem + 24576;
  const int tid = threadIdx.x, lane = tid & 63, wave = tid >> 6;
  const int wrow = (wave>>1)*64, wcol = (wave&1)*64;
  f32x4 acc[4][4];
  f32x4 z = {0.f,0.f,0.f,0.f};
  #pragma unroll
  for (int m_=0;m_<4;++m_) for (int n_=0;n_<4;++n_) acc[m_][n_] = z;
  int b = blockIdx.z, m0 = blockIdx.x*128, n0 = blockIdx.y*128;
  const u16* A = Q  + (long)b*NN*DM;
  const u16* B = Km + (long)b*NN*DM;

  stage2(A, B, DM, m0, n0, 0, sA0, sB0, tid, wave);
  __syncthreads();
  stage2(A, B, DM, m0, n0, 64, sA1, sB1, tid, wave);
  compute64(sA0, sB0, lane, wrow, wcol, acc);
  __syncthreads();                 // drains tile-1 loads; all waves done with sA0/sB0
  compute64(sA1, sB1, lane, wrow, wcol, acc);

  // C tile -> LDS (region sA0+sB0, disjoint from sA1/sB1 being read above)
  u16* sS = smem;                  // [128][128] bf16, stride 128
  #pragma unroll
  for (int m_=0;m_<4;++m_)
    #pragma unroll
    for (int n_=0;n_<4;++n_)
      #pragma unroll
      for (int r=0;r<4;++r){
        int row = wrow + m_*16 + (lane>>4)*4 + r;
        int col = wcol + n_*16 + (lane & 15);
        sS[row*128 + col] = f2bf(acc[m_][n_][r]);
      }
  __syncthreads();

  // coalesced store: 2048 chunks of 16B; wave covers 4 rows x 256B contiguous
  u16* Sb = S + (long)b*NN*NN + (long)m0*NN + n0;
  #pragma unroll
  for (int i = 0; i < 8; ++i){
    int ci = i*256 + tid;
    int row = ci >> 4, c = ci & 15;
    *(short8*)(Sb + (long)row*NN + c*8) = *(const short8*)&sS[row*128 + c*8];
  }
}

// ---------- K5: M[b,l] = max_s S[b,l,idx[l,s]] - sum_s(...)/1024 ----------
__global__ void k_mscore(const u16* __restrict__ S, const int* __restrict__ idx, float* __restrict__ M){
  int g    = blockIdx.x*4 + (threadIdx.x >> 6);   // one wave per (b,l)
  int lane = threadIdx.x & 63;
  int b = g >> 10, l = g & 1023;
  const u16* Srow = S + (long)b*NN*NN + (long)l*NN;
  const int* ir = idx + l*SK;
  float mx = -1e30f, sm = 0.f;
  for (int s = lane; s < SK; s += 64){
    float v = bf2f(Srow[ir[s]]);
    mx = fmaxf(mx, v); sm += v;
  }
  #pragma unroll
  for (int o=32;o;o>>=1){ mx = fmaxf(mx, __shfl_xor(mx,o)); sm += __shfl_xor(sm,o); }
  if (lane == 0) M[g] = mx - sm * (1.0f/1024.0f);
}

// ---------- K6a: partial ranks (blocks 0..255) + V column-mean (blocks 256..271) ----------
__global__ __launch_bounds__(256) void k_rankvm(const float* __restrict__ M, int* __restrict__ partial,
                                                const u16* __restrict__ V, float* __restrict__ vmean){
  __shared__ float sC[64];
  __shared__ float red[16][128];
  int blk = blockIdx.x, t = threadIdx.x;
  if (blk < 256){
    int jc = blk & 15, b = blk >> 4;
    const float* Mb = M + b*NN;
    if (t < 64) sC[t] = Mb[jc*64 + t];
    __syncthreads();
    int j0 = jc*64;
    float mi[4];
    int cnt[4] = {0,0,0,0};
    #pragma unroll
    for (int r=0;r<4;++r) mi[r] = Mb[t + r*256];
    for (int j = 0; j < 64; ++j){
      float mj = sC[j];
      int jg = j0 + j;
      #pragma unroll
      for (int r=0;r<4;++r){
        int i = t + r*256;
        cnt[r] += (mj > mi[r]) || (mj == mi[r] && jg < i);
      }
    }
    int* pb = partial + (b*16 + jc)*NN;
    #pragma unroll
    for (int r=0;r<4;++r) pb[t + r*256] = cnt[r];
  } else {
    int b = blk - 256;
    int d8 = t & 15, seg = t >> 4;
    const u16* Vb = V + (long)b*KTOT + seg*64*DM + d8*8;
    float acc[8] = {0,0,0,0,0,0,0,0};
    for (int l = 0; l < 64; ++l){
      short8 v = *(const short8*)(Vb + l*DM);
      #pragma unroll
      for (int j=0;j<8;++j) acc[j] += bf2f((u16)v[j]);
    }
    #pragma unroll
    for (int j=0;j<8;++j) red[seg][d8*8+j] = acc[j];
    __syncthreads();
    if (t < 128){
      float s = 0.f;
      #pragma unroll
      for (int g=0;g<16;++g) s += red[g][t];
      vmean[b*DM + t] = s * (1.0f/1024.0f);
    }
  }
}

// ---------- K6b: sum partial ranks -> mtop + selmap ----------
__global__ __launch_bounds__(1024) void k_sel(const int* __restrict__ partial, int* __restrict__ mtop,
                                              int* __restrict__ selmap){
  int b = blockIdx.x, i = threadIdx.x;
  int cnt = 0;
  #pragma unroll
  for (int jc = 0; jc < 16; ++jc) cnt += partial[(b*16 + jc)*NN + i];
  selmap[b*NN + i] = (cnt < SK) ? cnt : -1;
  if (cnt < SK) mtop[b*SK + cnt] = i;
}

// ---------- K9: softmax(S_row/sqrt(d)) @ V for top-140 rows, 4 rows/block ----------
// PV: dg = t&15 (coalesced V loads), kg = t>>4; reduce shfl(16,32) + LDS cross-wave.
__global__ __launch_bounds__(256) void k_attn(const u16* __restrict__ S, const u16* __restrict__ V,
                                              const int* __restrict__ mtop, float* __restrict__ upd){
  __shared__ float sE[4][1024];
  __shared__ float redM[4][4];
  __shared__ float redS[4][4];
  __shared__ float sP[4][4][128];   // [wave][row][d] 8KB
  int b = blockIdx.y, u0 = blockIdx.x*4, t = threadIdx.x;
  int lane = t & 63, wave = t >> 6;
  const float inv = 0.08838834764831845f;   // 1/sqrt(128)

  int rows[4];
  #pragma unroll
  for (int r=0;r<4;++r) rows[r] = mtop[b*SK + u0 + r];

  float sv[4][4];
  float pm[4];
  const u16* Sb = S + (long)b*NN*NN;
  #pragma unroll
  for (int r=0;r<4;++r){
    ushort4 raw = ((const ushort4*)(Sb + (long)rows[r]*NN))[t];
    sv[r][0] = bf2f(raw.x)*inv; sv[r][1] = bf2f(raw.y)*inv;
    sv[r][2] = bf2f(raw.z)*inv; sv[r][3] = bf2f(raw.w)*inv;
    pm[r] = fmaxf(fmaxf(sv[r][0],sv[r][1]), fmaxf(sv[r][2],sv[r][3]));
  }
  #pragma unroll
  for (int o=32;o;o>>=1)
    #pragma unroll
    for (int r=0;r<4;++r) pm[r] = fmaxf(pm[r], __shfl_xor(pm[r],o));
  if (lane == 0){
    #pragma unroll
    for (int r=0;r<4;++r) redM[wave][r] = pm[r];
  }
  __syncthreads();
  float mx[4], ps[4];
  #pragma unroll
  for (int r=0;r<4;++r)
    mx[r] = fmaxf(fmaxf(redM[0][r],redM[1][r]), fmaxf(redM[2][r],redM[3][r]));
  #pragma unroll
  for (int r=0;r<4;++r){
    float s = 0.f;
    #pragma unroll
    for (int j=0;j<4;++j){
      float e = __expf(sv[r][j] - mx[r]);
      sE[r][t*4+j] = e;
      s += e;
    }
    ps[r] = s;
  }
  #pragma unroll
  for (int o=32;o;o>>=1)
    #pragma unroll
    for (int r=0;r<4;++r) ps[r] += __shfl_xor(ps[r],o);
  if (lane == 0){
    #pragma unroll
    for (int r=0;r<4;++r) redS[wave][r] = ps[r];
  }
  __syncthreads();
  float rZ[4];
  #pragma unroll
  for (int r=0;r<4;++r)
    rZ[r] = 1.0f / (redS[0][r]+redS[1][r]+redS[2][r]+redS[3][r]);

  // ---- PV, coalesced: dg = t&15, kg = t>>4 ----
  int dg = t & 15;
  int kg = t >> 4;
  const u16* Vb = V + (long)b*KTOT + dg*8;
  float acc[4][8];
  #pragma unroll
  for (int r=0;r<4;++r)
    #pragma unroll
    for (int j=0;j<8;++j) acc[r][j] = 0.f;

  for (int k = kg; k < NN; k += 16){
    short8 v = *(const short8*)(Vb + (long)k*DM);
    float vf[8];
    #pragma unroll
    for (int j=0;j<8;++j) vf[j] = bf2f((u16)v[j]);
    #pragma unroll
    for (int r=0;r<4;++r){
      float e = sE[r][k];
      #pragma unroll
      for (int j=0;j<8;++j) acc[r][j] += e * vf[j];
    }
  }

  // reduce over this wave's 4 kg values (lane bits 4,5)
  #pragma unroll
  for (int o=16;o<64;o<<=1)
    #pragma unroll
    for (int r=0;r<4;++r)
      #pragma unroll
      for (int j=0;j<8;++j) acc[r][j] += __shfl_xor(acc[r][j], o);

  if ((t & 63) < 16){
    #pragma unroll
    for (int r=0;r<4;++r)
      #pragma unroll
      for (int j=0;j<8;++j) sP[wave][r][dg*8+j] = acc[r][j];
  }
  __syncthreads();
  if (t < 128){
    #pragma unroll
    for (int r=0;r<4;++r){
      float s = sP[0][r][t] + sP[1][r][t] + sP[2][r][t] + sP[3][r][t];
      upd[((long)b*SK + u0 + r)*DM + t] = s * rZ[r];
    }
  }
}

// ---------- K11: final GEMV partials: (ctx+A) @ W_final ; wf2 is [k][c] contiguous ----------
__global__ __launch_bounds__(256) void k_final(const float* __restrict__ upd, const float* __restrict__ vmean,
                                               const int* __restrict__ selmap,
                                               const u16* __restrict__ Aad,
                                               const u16* __restrict__ wf2, float* __restrict__ part){
  int b = blockIdx.x, ch = blockIdx.y, t = threadIdx.x;
  long base = (long)b * KTOT;
  int k0 = ch * 4096;
  float acc[NC] = {0.f};
  for (int k = k0 + t; k < k0 + 4096; k += 256){
    int l = k >> 7, d = k & 127;
    int sel = selmap[b*NN + l];
    float c = (sel >= 0) ? upd[((long)b*SK + sel)*DM + d] : vmean[b*DM + d];
    float v = c + bf2f(Aad[base + k]);
    const u32* w32 = (const u32*)(wf2 + (long)k*NC);   // 10 bf16 = 20B contiguous
    #pragma unroll
    for (int cc = 0; cc < 5; ++cc){
      u32 w = w32[cc];
      acc[2*cc]   += v * bf2f((u16)(w & 0xFFFF));
      acc[2*cc+1] += v * bf2f((u16)(w >> 16));
    }
  }
  __shared__ float lred[40];
  int lane = t & 63, wave = t >> 6;
  #pragma unroll
  for (int c = 0; c < NC; ++c){
    float v = acc[c];
    #pragma unroll
    for (int o=32;o;o>>=1) v += __shfl_xor(v,o);
    if (lane == 0) lred[wave*NC + c] = v;
  }
  __syncthreads();
  if (t < NC) part[(b*32 + ch)*NC + t] = lred[t] + lred[NC+t] + lred[2*NC+t] + lred[3*NC+t];
}

// ---------- K12: reduce partials + bias -> out ----------
__global__ void k_out(const float* __restrict__ part, const float* __restrict__ bfin, float* __restrict__ out){
  int t = threadIdx.x;
  if (t < BB*NC){
    int b = t / NC, c = t % NC;
    float s = bfin[c];
    #pragma unroll
    for (int ch = 0; ch < 32; ++ch) s += part[(b*32 + ch)*NC + c];
    out[t] = s;
  }
}

// ---------- launch ----------
extern "C" void kernel_launch(void* const* d_in, const int* in_sizes, int n_in,
                              void* d_out, int out_size, void* d_ws, size_t ws_size,
                              hipStream_t stream){
  const float* emb  = (const float*)d_in[0];
  const int*   idxs = (const int*)  d_in[1];
  const float* Wlin = (const float*)d_in[2];
  const float* blin = (const float*)d_in[3];
  const float* Wq   = (const float*)d_in[4];
  const float* Wk   = (const float*)d_in[5];
  const float* Wv   = (const float*)d_in[6];
  const float* Wadd = (const float*)d_in[7];
  const float* badd = (const float*)d_in[8];
  const float* Wfin = (const float*)d_in[9];
  const float* bfin = (const float*)d_in[10];
  float* out = (float*)d_out;

  char* p = (char*)d_ws;
  auto alloc = [&](size_t bytes)->char*{ char* r = p; p += (bytes + 255) & ~(size_t)255; return r; };
  u16*   wlinT  = (u16*)  alloc((size_t)DL*DML*2);
  u16*   w4T    = (u16*)  alloc((size_t)4*DM*DL*2);
  u16*   x_bf   = (u16*)  alloc((size_t)BB*NN*DL*2);
  u16*   q_bf   = (u16*)  alloc((size_t)BB*NN*DM*2);
  u16*   k_bf   = (u16*)  alloc((size_t)BB*NN*DM*2);
  u16*   v_bf   = (u16*)  alloc((size_t)BB*NN*DM*2);
  u16*   a_bf   = (u16*)  alloc((size_t)BB*NN*DM*2);
  u16*   s_bf   = (u16*)  alloc((size_t)BB*NN*NN*2);
  float* m_f    = (float*)alloc((size_t)BB*NN*4);
  int*   rankp  = (int*)  alloc((size_t)BB*16*NN*4);
  int*   mtop   = (int*)  alloc((size_t)BB*SK*4);
  int*   selmap = (int*)  alloc((size_t)BB*NN*4);
  float* vmean  = (float*)alloc((size_t)BB*DM*4);
  float* upd    = (float*)alloc((size_t)BB*SK*DM*4);
  u16*   wf2    = (u16*)  alloc((size_t)KTOT*NC*2);
  float* part   = (float*)alloc((size_t)BB*32*NC*4);

  // 1: pack weights + wf2 (no transpose)
  k_prep<<<dim3(1792), dim3(256), 0, stream>>>(Wlin, Wq, Wk, Wv, Wadd, wlinT, w4T, Wfin, wf2);
  // 2: x = emb @ Wlin + b  (BN=128 split for 2x occupancy)
  k_gemm_x<<<dim3(256, 2), dim3(256), 0, stream>>>(emb, wlinT, blin, x_bf);
  // 3: Q,K,V,A
  k_gemm_qkva<<<dim3(128, 4), dim3(256), 0, stream>>>(x_bf, w4T, badd, q_bf, k_bf, v_bf, a_bf);
  // 4: S = Q K^T per batch -> bf16, coalesced epilogue
  k_gemm_s<<<dim3(8, 8, 16), dim3(256), 0, stream>>>(q_bf, k_bf, s_bf);
  // 5: M scores
  k_mscore<<<dim3(BB*NN/4), dim3(256), 0, stream>>>(s_bf, idxs, m_f);
  // 6: partial ranks + vmean
  k_rankvm<<<dim3(272), dim3(256), 0, stream>>>(m_f, rankp, v_bf, vmean);
  // 7: select top-140
  k_sel<<<dim3(BB), dim3(1024), 0, stream>>>(rankp, mtop, selmap);
  // 8: attention rows -> compact upd (coalesced PV)
  k_attn<<<dim3(SK/4, BB), dim3(256), 0, stream>>>(s_bf, v_bf, mtop, upd);
  // 9/10: final projection
  k_final<<<dim3(BB, 32), dim3(256), 0, stream>>>(upd, vmean, selmap, a_bf, wf2, part);
  k_out<<<dim3(1), dim3(256), 0, stream>>>(part, bfin, out);
}

// Round 13
// 113.181 us; speedup vs baseline: 1.1220x; 1.0235x over previous
//
#include <hip/hip_runtime.h>

typedef __attribute__((ext_vector_type(8))) short short8;
typedef __attribute__((ext_vector_type(4))) float f32x4;
typedef unsigned short u16;
typedef unsigned int u32;
typedef __attribute__((address_space(1))) const u32 gu32;
typedef __attribute__((address_space(3))) u32 lu32;

// ---------- bf16 helpers ----------
__device__ __forceinline__ u16 f2bf(float f){
  unsigned u = __float_as_uint(f);
  u += 0x7FFF + ((u >> 16) & 1);          // round-to-nearest-even
  return (u16)(u >> 16);
}
__device__ __forceinline__ float bf2f(u16 h){ return __uint_as_float(((unsigned)h) << 16); }

// ---------- problem constants ----------
#define BB   16
#define NN   1024
#define DML  512
#define DL   256
#define DM   128
#define NC   10
#define SK   140
#define KTOT (NN*DM)          // 131072

// ---------- K_prep: pack weights bf16-transposed | convert W_final -> bf16 [k][c] ----------
__global__ void k_prep(const float* __restrict__ Wlin, const float* __restrict__ Wq,
                       const float* __restrict__ Wk, const float* __restrict__ Wv,
                       const float* __restrict__ Wadd,
                       u16* __restrict__ wlinT, u16* __restrict__ w4T,
                       const float* __restrict__ Wf, u16* __restrict__ wf2){
  int blk = blockIdx.x, t = threadIdx.x;
  if (blk < 512){
    int id = blk*256 + t;              // 131072
    {
      int j = id >> 9;        // 0..255  (DL)
      int k = id & 511;       // 0..511  (DML)
      wlinT[id] = f2bf(Wlin[k*DL + j]);
    }
    {
      int j = id >> 8;        // 0..511  (4*DM)
      int k = id & 255;       // 0..255  (DL)
      const float* src = (j < 128) ? Wq : (j < 256) ? Wk : (j < 384) ? Wv : Wadd;
      int jj = j & 127;
      w4T[id] = f2bf(src[k*DM + jj]);
    }
  } else {
    // W_final is already [k][c] row-major: pure f32->bf16 convert, vectorized
    int i4 = (blk-512)*256 + t;        // 327,680 float4s  (1,310,720 elems)
    float4 v = ((const float4*)Wf)[i4];
    ushort4 o; o.x=f2bf(v.x); o.y=f2bf(v.y); o.z=f2bf(v.z); o.w=f2bf(v.w);
    ((ushort4*)wf2)[i4] = o;
  }
}

// ---------- GEMM staging helpers (128-row tiles, BK=64) ----------
__device__ __forceinline__ void stage2(const u16* __restrict__ A, const u16* __restrict__ B,
                                       int K, int m0, int n0, int kb,
                                       u16* sA, u16* sB, int tid, int wave){
  #pragma unroll
  for (int i = 0; i < 4; ++i){
    int ci  = i*256 + tid;
    int row = ci >> 3;
    int kc  = (ci & 7) ^ (row & 7);
    __builtin_amdgcn_global_load_lds((gu32*)(A + (long)(m0+row)*K + kb + kc*8),
                                     (lu32*)(sA + (i*256 + wave*64)*8), 16, 0, 0);
    __builtin_amdgcn_global_load_lds((gu32*)(B + (long)(n0+row)*K + kb + kc*8),
                                     (lu32*)(sB + (i*256 + wave*64)*8), 16, 0, 0);
  }
}
// MFMA over one 64-wide K tile (128x128 tile, 4 waves of 64x64)
__device__ __forceinline__ void compute64(const u16* sA, const u16* sB,
                                          int lane, int wrow, int wcol, f32x4 acc[4][4]){
  #pragma unroll
  for (int kk = 0; kk < 2; ++kk){
    short8 af[4], bfr[4];
    int cb = kk*4 + (lane >> 4);
    #pragma unroll
    for (int m_=0; m_<4; ++m_){
      int row = wrow + m_*16 + (lane & 15);
      af[m_] = *(const short8*)&sA[row*64 + ((cb ^ (row & 7)) << 3)];
    }
    #pragma unroll
    for (int n_=0; n_<4; ++n_){
      int row = wcol + n_*16 + (lane & 15);
      bfr[n_] = *(const short8*)&sB[row*64 + ((cb ^ (row & 7)) << 3)];
    }
    #pragma unroll
    for (int m_=0; m_<4; ++m_)
      #pragma unroll
      for (int n_=0; n_<4; ++n_)
        acc[m_][n_] = __builtin_amdgcn_mfma_f32_16x16x32_bf16(af[m_], bfr[n_], acc[m_][n_], 0, 0, 0);
  }
}
// double-buffered core: 1 barrier per K-step, stage(next) overlaps compute(cur)
// NOTE: for even nt (= K/64), final compute reads sA1/sB1, leaving sA0/sB0 free.
__device__ __forceinline__ void gemm_core_db(const u16* __restrict__ A, const u16* __restrict__ B,
                                             int K, int m0, int n0,
                                             u16* sA0, u16* sB0, u16* sA1, u16* sB1,
                                             f32x4 acc[4][4]){
  const int tid  = threadIdx.x;
  const int lane = tid & 63;
  const int wave = tid >> 6;
  const int wrow = (wave >> 1) * 64;
  const int wcol = (wave & 1) * 64;
  u16 *cA = sA0, *cB = sB0, *nA = sA1, *nB = sB1;
  stage2(A, B, K, m0, n0, 0, cA, cB, tid, wave);
  __syncthreads();
  int nt = K >> 6;
  for (int t = 0; t < nt-1; ++t){
    stage2(A, B, K, m0, n0, (t+1)*64, nA, nB, tid, wave);
    compute64(cA, cB, lane, wrow, wcol, acc);
    __syncthreads();
    u16* x;
    x = cA; cA = nA; nA = x;
    x = cB; cB = nB; nB = x;
  }
  compute64(cA, cB, lane, wrow, wcol, acc);
}

// ---------- K2: x = emb(f32) @ W_lin + b_lin -> bf16 ; BM=64 x BN=128, coalesced epilogue ----------
__global__ __launch_bounds__(256) void k_gemm_x(const float* __restrict__ A, const u16* __restrict__ B,
                                                const float* __restrict__ bias, u16* __restrict__ out){
  __shared__ u16 smem[12288];   // 24KB: sA = [0,4096), sB = [4096,12288)
  u16* sA = smem;
  u16* sB = smem + 4096;
  const int tid  = threadIdx.x;
  const int lane = tid & 63;
  const int wave = tid >> 6;
  const int wrow = (wave >> 1) * 32;
  const int wcol = (wave & 1) * 64;
  int m0 = blockIdx.x*64, n0 = blockIdx.y*128;
  f32x4 acc[2][4];
  f32x4 z = {0.f,0.f,0.f,0.f};
  #pragma unroll
  for (int m_=0;m_<2;++m_) for (int n_=0;n_<4;++n_) acc[m_][n_] = z;

  f32x4 ra[4];      // A: 16 f32 per thread (row = tid>>2, two chunks kc=aq*2, aq*2+1)
  short8 rb[4];     // B: 4 chunks per thread
  const int arow = tid >> 2, aq = tid & 3;

  // prologue: tile 0
  {
    const float* src = A + (long)(m0+arow)*DML + aq*16;
    ra[0] = ((const f32x4*)src)[0]; ra[1] = ((const f32x4*)src)[1];
    ra[2] = ((const f32x4*)src)[2]; ra[3] = ((const f32x4*)src)[3];
    #pragma unroll
    for (int i=0;i<4;++i){
      int ci = i*256 + tid, row = ci>>3, kc = ci&7;
      rb[i] = *(const short8*)(B + (long)(n0+row)*DML + kc*8);
    }
  }
  {
    short8 o0, o1;
    #pragma unroll
    for (int j=0;j<4;++j){ o0[j]=(short)f2bf(ra[0][j]); o0[4+j]=(short)f2bf(ra[1][j]);
                           o1[j]=(short)f2bf(ra[2][j]); o1[4+j]=(short)f2bf(ra[3][j]); }
    int kc0 = aq*2, kc1 = aq*2+1;
    *(short8*)&sA[arow*64 + ((kc0 ^ (arow&7))<<3)] = o0;
    *(short8*)&sA[arow*64 + ((kc1 ^ (arow&7))<<3)] = o1;
    #pragma unroll
    for (int i=0;i<4;++i){
      int ci = i*256 + tid, row = ci>>3, kc = ci&7;
      *(short8*)&sB[row*64 + ((kc ^ (row&7))<<3)] = rb[i];
    }
  }
  __syncthreads();

  for (int tt = 0; tt < 8; ++tt){
    if (tt < 7){
      int kb = (tt+1)*64;
      const float* src = A + (long)(m0+arow)*DML + kb + aq*16;
      ra[0] = ((const f32x4*)src)[0]; ra[1] = ((const f32x4*)src)[1];
      ra[2] = ((const f32x4*)src)[2]; ra[3] = ((const f32x4*)src)[3];
      #pragma unroll
      for (int i=0;i<4;++i){
        int ci = i*256 + tid, row = ci>>3, kc = ci&7;
        rb[i] = *(const short8*)(B + (long)(n0+row)*DML + kb + kc*8);
      }
    }
    #pragma unroll
    for (int kk = 0; kk < 2; ++kk){
      short8 af[2], bfr[4];
      int cb = kk*4 + (lane >> 4);
      #pragma unroll
      for (int m_=0; m_<2; ++m_){
        int row = wrow + m_*16 + (lane & 15);
        af[m_] = *(const short8*)&sA[row*64 + ((cb ^ (row & 7)) << 3)];
      }
      #pragma unroll
      for (int n_=0; n_<4; ++n_){
        int row = wcol + n_*16 + (lane & 15);
        bfr[n_] = *(const short8*)&sB[row*64 + ((cb ^ (row & 7)) << 3)];
      }
      #pragma unroll
      for (int m_=0; m_<2; ++m_)
        #pragma unroll
        for (int n_=0; n_<4; ++n_)
          acc[m_][n_] = __builtin_amdgcn_mfma_f32_16x16x32_bf16(af[m_], bfr[n_], acc[m_][n_], 0, 0, 0);
    }
    __syncthreads();                 // after tt=7 this guarantees all waves done reading sB
    if (tt < 7){
      short8 o0, o1;
      #pragma unroll
      for (int j=0;j<4;++j){ o0[j]=(short)f2bf(ra[0][j]); o0[4+j]=(short)f2bf(ra[1][j]);
                             o1[j]=(short)f2bf(ra[2][j]); o1[4+j]=(short)f2bf(ra[3][j]); }
      int kc0 = aq*2, kc1 = aq*2+1;
      *(short8*)&sA[arow*64 + ((kc0 ^ (arow&7))<<3)] = o0;
      *(short8*)&sA[arow*64 + ((kc1 ^ (arow&7))<<3)] = o1;
      #pragma unroll
      for (int i=0;i<4;++i){
        int ci = i*256 + tid, row = ci>>3, kc = ci&7;
        *(short8*)&sB[row*64 + ((kc ^ (row&7))<<3)] = rb[i];
      }
      __syncthreads();
    }
  }

  // C tile -> LDS (sB region, 64x128 bf16 = 16KB), then coalesced store
  u16* sC = sB;
  #pragma unroll
  for (int m_=0;m_<2;++m_)
    #pragma unroll
    for (int n_=0;n_<4;++n_)
      #pragma unroll
      for (int rr=0;rr<4;++rr){
        int row = wrow + m_*16 + (lane>>4)*4 + rr;
        int col = wcol + n_*16 + (lane & 15);
        sC[row*128 + col] = f2bf(acc[m_][n_][rr] + bias[n0 + col]);
      }
  __syncthreads();
  #pragma unroll
  for (int i = 0; i < 4; ++i){
    int ci = i*256 + tid;
    int row = ci >> 4, c = ci & 15;
    *(short8*)(out + (long)(m0+row)*DL + n0 + c*8) = *(const short8*)&sC[row*128 + c*8];
  }
}

// ---------- K3: [Q|K|V|A] = x @ [Wq|Wk|Wv|Wadd], coalesced epilogue ----------
__global__ __launch_bounds__(256) void k_gemm_qkva(const u16* __restrict__ A, const u16* __restrict__ B,
                                                   const float* __restrict__ badd,
                                                   u16* __restrict__ oq, u16* __restrict__ ok,
                                                   u16* __restrict__ ov, u16* __restrict__ oa){
  __shared__ u16 smem[32768];   // 64KB; nt=4 even -> final compute reads smem[16384..), so [0,16384) free for C
  f32x4 acc[4][4];
  f32x4 z = {0.f,0.f,0.f,0.f};
  #pragma unroll
  for (int m_=0;m_<4;++m_) for (int n_=0;n_<4;++n_) acc[m_][n_] = z;
  int m0 = blockIdx.x*128;
  int tn = blockIdx.y;              // 0=Q 1=K 2=V 3=A
  gemm_core_db(A, B, DL, m0, tn*128, smem, smem+8192, smem+16384, smem+24576, acc);
  int tid = threadIdx.x, lane = tid & 63, wave = tid >> 6;
  int wrow = (wave>>1)*64, wcol = (wave&1)*64;
  u16* dst = (tn==0) ? oq : (tn==1) ? ok : (tn==2) ? ov : oa;

  u16* sC = smem;                   // [128][128] bf16
  #pragma unroll
  for (int m_=0;m_<4;++m_)
    #pragma unroll
    for (int n_=0;n_<4;++n_)
      #pragma unroll
      for (int r=0;r<4;++r){
        int row = wrow + m_*16 + (lane>>4)*4 + r;
        int col = wcol + n_*16 + (lane & 15);
        float v = acc[m_][n_][r];
        if (tn == 3) v += badd[col];
        sC[row*128 + col] = f2bf(v);
      }
  __syncthreads();
  u16* db = dst + (long)m0*DM;
  #pragma unroll
  for (int i = 0; i < 8; ++i){
    int ci = i*256 + tid;
    int row = ci >> 4, c = ci & 15;
    *(short8*)(db + (long)row*DM + c*8) = *(const short8*)&sC[row*128 + c*8];
  }
}

// ---------- K4: S[b] = Q[b] @ K[b]^T -> bf16, LDS-staged COALESCED epilogue ----------
__global__ __launch_bounds__(256) void k_gemm_s(const u16* __restrict__ Q, const u16* __restrict__ Km,
                                                u16* __restrict__ S){
  __shared__ u16 smem[32768];     // 64KB: 4x8192 staging; first 16384 reused for C tile
  u16* sA0 = smem;
  u16* sB0 = smem + 8192;
  u16* sA1 = smem + 16384;
  u16* sB1 = smem + 24576;
  const int tid = threadIdx.x, lane = tid & 63, wave = tid >> 6;
  const int wrow = (wave>>1)*64, wcol = (wave&1)*64;
  f32x4 acc[4][4];
  f32x4 z = {0.f,0.f,0.f,0.f};
  #pragma unroll
  for (int m_=0;m_<4;++m_) for (int n_=0;n_<4;++n_) acc[m_][n_] = z;
  int b = blockIdx.z, m0 = blockIdx.x*128, n0 = blockIdx.y*128;
  const u16* A = Q  + (long)b*NN*DM;
  const u16* B = Km + (long)b*NN*DM;

  stage2(A, B, DM, m0, n0, 0, sA0, sB0, tid, wave);
  __syncthreads();
  stage2(A, B, DM, m0, n0, 64, sA1, sB1, tid, wave);
  compute64(sA0, sB0, lane, wrow, wcol, acc);
  __syncthreads();                 // drains tile-1 loads; all waves done with sA0/sB0
  compute64(sA1, sB1, lane, wrow, wcol, acc);

  // C tile -> LDS (region sA0+sB0, disjoint from sA1/sB1 being read above)
  u16* sS = smem;                  // [128][128] bf16, stride 128
  #pragma unroll
  for (int m_=0;m_<4;++m_)
    #pragma unroll
    for (int n_=0;n_<4;++n_)
      #pragma unroll
      for (int r=0;r<4;++r){
        int row = wrow + m_*16 + (lane>>4)*4 + r;
        int col = wcol + n_*16 + (lane & 15);
        sS[row*128 + col] = f2bf(acc[m_][n_][r]);
      }
  __syncthreads();

  // coalesced store: 2048 chunks of 16B; wave covers 4 rows x 256B contiguous
  u16* Sb = S + (long)b*NN*NN + (long)m0*NN + n0;
  #pragma unroll
  for (int i = 0; i < 8; ++i){
    int ci = i*256 + tid;
    int row = ci >> 4, c = ci & 15;
    *(short8*)(Sb + (long)row*NN + c*8) = *(const short8*)&sS[row*128 + c*8];
  }
}

// ---------- K5: M[b,l] = max_s S[b,l,idx[l,s]] - sum_s(...)/1024 ----------
__global__ void k_mscore(const u16* __restrict__ S, const int* __restrict__ idx, float* __restrict__ M){
  int g    = blockIdx.x*4 + (threadIdx.x >> 6);   // one wave per (b,l)
  int lane = threadIdx.x & 63;
  int b = g >> 10, l = g & 1023;
  const u16* Srow = S + (long)b*NN*NN + (long)l*NN;
  const int* ir = idx + l*SK;
  float mx = -1e30f, sm = 0.f;
  for (int s = lane; s < SK; s += 64){
    float v = bf2f(Srow[ir[s]]);
    mx = fmaxf(mx, v); sm += v;
  }
  #pragma unroll
  for (int o=32;o;o>>=1){ mx = fmaxf(mx, __shfl_xor(mx,o)); sm += __shfl_xor(sm,o); }
  if (lane == 0) M[g] = mx - sm * (1.0f/1024.0f);
}

// ---------- K6a: partial ranks (blocks 0..255) + V column-mean (blocks 256..271) ----------
__global__ __launch_bounds__(256) void k_rankvm(const float* __restrict__ M, int* __restrict__ partial,
                                                const u16* __restrict__ V, float* __restrict__ vmean){
  __shared__ float sC[64];
  __shared__ float red[16][128];
  int blk = blockIdx.x, t = threadIdx.x;
  if (blk < 256){
    int jc = blk & 15, b = blk >> 4;
    const float* Mb = M + b*NN;
    if (t < 64) sC[t] = Mb[jc*64 + t];
    __syncthreads();
    int j0 = jc*64;
    float mi[4];
    int cnt[4] = {0,0,0,0};
    #pragma unroll
    for (int r=0;r<4;++r) mi[r] = Mb[t + r*256];
    for (int j = 0; j < 64; ++j){
      float mj = sC[j];
      int jg = j0 + j;
      #pragma unroll
      for (int r=0;r<4;++r){
        int i = t + r*256;
        cnt[r] += (mj > mi[r]) || (mj == mi[r] && jg < i);
      }
    }
    int* pb = partial + (b*16 + jc)*NN;
    #pragma unroll
    for (int r=0;r<4;++r) pb[t + r*256] = cnt[r];
  } else {
    int b = blk - 256;
    int d8 = t & 15, seg = t >> 4;
    const u16* Vb = V + (long)b*KTOT + seg*64*DM + d8*8;
    float acc[8] = {0,0,0,0,0,0,0,0};
    for (int l = 0; l < 64; ++l){
      short8 v = *(const short8*)(Vb + l*DM);
      #pragma unroll
      for (int j=0;j<8;++j) acc[j] += bf2f((u16)v[j]);
    }
    #pragma unroll
    for (int j=0;j<8;++j) red[seg][d8*8+j] = acc[j];
    __syncthreads();
    if (t < 128){
      float s = 0.f;
      #pragma unroll
      for (int g=0;g<16;++g) s += red[g][t];
      vmean[b*DM + t] = s * (1.0f/1024.0f);
    }
  }
}

// ---------- K6b: sum partial ranks -> mtop + selmap ----------
__global__ __launch_bounds__(1024) void k_sel(const int* __restrict__ partial, int* __restrict__ mtop,
                                              int* __restrict__ selmap){
  int b = blockIdx.x, i = threadIdx.x;
  int cnt = 0;
  #pragma unroll
  for (int jc = 0; jc < 16; ++jc) cnt += partial[(b*16 + jc)*NN + i];
  selmap[b*NN + i] = (cnt < SK) ? cnt : -1;
  if (cnt < SK) mtop[b*SK + cnt] = i;
}

// ---------- K9: softmax(S_row/sqrt(d)) @ V for top-140 rows, 4 rows/block ----------
// PV: dg = t&15 (coalesced V loads), kg = t>>4; reduce shfl(16,32) + LDS cross-wave.
__global__ __launch_bounds__(256) void k_attn(const u16* __restrict__ S, const u16* __restrict__ V,
                                              const int* __restrict__ mtop, float* __restrict__ upd){
  __shared__ float sE[4][1024];
  __shared__ float redM[4][4];
  __shared__ float redS[4][4];
  __shared__ float sP[4][4][128];   // [wave][row][d] 8KB
  int b = blockIdx.y, u0 = blockIdx.x*4, t = threadIdx.x;
  int lane = t & 63, wave = t >> 6;
  const float inv = 0.08838834764831845f;   // 1/sqrt(128)

  int rows[4];
  #pragma unroll
  for (int r=0;r<4;++r) rows[r] = mtop[b*SK + u0 + r];

  float sv[4][4];
  float pm[4];
  const u16* Sb = S + (long)b*NN*NN;
  #pragma unroll
  for (int r=0;r<4;++r){
    ushort4 raw = ((const ushort4*)(Sb + (long)rows[r]*NN))[t];
    sv[r][0] = bf2f(raw.x)*inv; sv[r][1] = bf2f(raw.y)*inv;
    sv[r][2] = bf2f(raw.z)*inv; sv[r][3] = bf2f(raw.w)*inv;
    pm[r] = fmaxf(fmaxf(sv[r][0],sv[r][1]), fmaxf(sv[r][2],sv[r][3]));
  }
  #pragma unroll
  for (int o=32;o;o>>=1)
    #pragma unroll
    for (int r=0;r<4;++r) pm[r] = fmaxf(pm[r], __shfl_xor(pm[r],o));
  if (lane == 0){
    #pragma unroll
    for (int r=0;r<4;++r) redM[wave][r] = pm[r];
  }
  __syncthreads();
  float mx[4], ps[4];
  #pragma unroll
  for (int r=0;r<4;++r)
    mx[r] = fmaxf(fmaxf(redM[0][r],redM[1][r]), fmaxf(redM[2][r],redM[3][r]));
  #pragma unroll
  for (int r=0;r<4;++r){
    float s = 0.f;
    #pragma unroll
    for (int j=0;j<4;++j){
      float e = __expf(sv[r][j] - mx[r]);
      sE[r][t*4+j] = e;
      s += e;
    }
    ps[r] = s;
  }
  #pragma unroll
  for (int o=32;o;o>>=1)
    #pragma unroll
    for (int r=0;r<4;++r) ps[r] += __shfl_xor(ps[r],o);
  if (lane == 0){
    #pragma unroll
    for (int r=0;r<4;++r) redS[wave][r] = ps[r];
  }
  __syncthreads();
  float rZ[4];
  #pragma unroll
  for (int r=0;r<4;++r)
    rZ[r] = 1.0f / (redS[0][r]+redS[1][r]+redS[2][r]+redS[3][r]);

  // ---- PV, coalesced: dg = t&15, kg = t>>4 ----
  int dg = t & 15;
  int kg = t >> 4;
  const u16* Vb = V + (long)b*KTOT + dg*8;
  float acc[4][8];
  #pragma unroll
  for (int r=0;r<4;++r)
    #pragma unroll
    for (int j=0;j<8;++j) acc[r][j] = 0.f;

  for (int k = kg; k < NN; k += 16){
    short8 v = *(const short8*)(Vb + (long)k*DM);
    float vf[8];
    #pragma unroll
    for (int j=0;j<8;++j) vf[j] = bf2f((u16)v[j]);
    #pragma unroll
    for (int r=0;r<4;++r){
      float e = sE[r][k];
      #pragma unroll
      for (int j=0;j<8;++j) acc[r][j] += e * vf[j];
    }
  }

  // reduce over this wave's 4 kg values (lane bits 4,5)
  #pragma unroll
  for (int o=16;o<64;o<<=1)
    #pragma unroll
    for (int r=0;r<4;++r)
      #pragma unroll
      for (int j=0;j<8;++j) acc[r][j] += __shfl_xor(acc[r][j], o);

  if ((t & 63) < 16){
    #pragma unroll
    for (int r=0;r<4;++r)
      #pragma unroll
      for (int j=0;j<8;++j) sP[wave][r][dg*8+j] = acc[r][j];
  }
  __syncthreads();
  if (t < 128){
    #pragma unroll
    for (int r=0;r<4;++r){
      float s = sP[0][r][t] + sP[1][r][t] + sP[2][r][t] + sP[3][r][t];
      upd[((long)b*SK + u0 + r)*DM + t] = s * rZ[r];
    }
  }
}

// ---------- K11: final GEMV partials: (ctx+A) @ W_final ; wf2 is [k][c] contiguous ----------
__global__ __launch_bounds__(256) void k_final(const float* __restrict__ upd, const float* __restrict__ vmean,
                                               const int* __restrict__ selmap,
                                               const u16* __restrict__ Aad,
                                               const u16* __restrict__ wf2, float* __restrict__ part){
  int b = blockIdx.x, ch = blockIdx.y, t = threadIdx.x;
  long base = (long)b * KTOT;
  int k0 = ch * 4096;
  float acc[NC] = {0.f};
  for (int k = k0 + t; k < k0 + 4096; k += 256){
    int l = k >> 7, d = k & 127;
    int sel = selmap[b*NN + l];
    float c = (sel >= 0) ? upd[((long)b*SK + sel)*DM + d] : vmean[b*DM + d];
    float v = c + bf2f(Aad[base + k]);
    const u32* w32 = (const u32*)(wf2 + (long)k*NC);   // 10 bf16 = 20B contiguous
    #pragma unroll
    for (int cc = 0; cc < 5; ++cc){
      u32 w = w32[cc];
      acc[2*cc]   += v * bf2f((u16)(w & 0xFFFF));
      acc[2*cc+1] += v * bf2f((u16)(w >> 16));
    }
  }
  __shared__ float lred[40];
  int lane = t & 63, wave = t >> 6;
  #pragma unroll
  for (int c = 0; c < NC; ++c){
    float v = acc[c];
    #pragma unroll
    for (int o=32;o;o>>=1) v += __shfl_xor(v,o);
    if (lane == 0) lred[wave*NC + c] = v;
  }
  __syncthreads();
  if (t < NC) part[(b*32 + ch)*NC + t] = lred[t] + lred[NC+t] + lred[2*NC+t] + lred[3*NC+t];
}

// ---------- K12: reduce partials + bias -> out ----------
__global__ void k_out(const float* __restrict__ part, const float* __restrict__ bfin, float* __restrict__ out){
  int t = threadIdx.x;
  if (t < BB*NC){
    int b = t / NC, c = t % NC;
    float s = bfin[c];
    #pragma unroll
    for (int ch = 0; ch < 32; ++ch) s += part[(b*32 + ch)*NC + c];
    out[t] = s;
  }
}

// ---------- launch ----------
extern "C" void kernel_launch(void* const* d_in, const int* in_sizes, int n_in,
                              void* d_out, int out_size, void* d_ws, size_t ws_size,
                              hipStream_t stream){
  const float* emb  = (const float*)d_in[0];
  const int*   idxs = (const int*)  d_in[1];
  const float* Wlin = (const float*)d_in[2];
  const float* blin = (const float*)d_in[3];
  const float* Wq   = (const float*)d_in[4];
  const float* Wk   = (const float*)d_in[5];
  const float* Wv   = (const float*)d_in[6];
  const float* Wadd = (const float*)d_in[7];
  const float* badd = (const float*)d_in[8];
  const float* Wfin = (const float*)d_in[9];
  const float* bfin = (const float*)d_in[10];
  float* out = (float*)d_out;

  char* p = (char*)d_ws;
  auto alloc = [&](size_t bytes)->char*{ char* r = p; p += (bytes + 255) & ~(size_t)255; return r; };
  u16*   wlinT  = (u16*)  alloc((size_t)DL*DML*2);
  u16*   w4T    = (u16*)  alloc((size_t)4*DM*DL*2);
  u16*   x_bf   = (u16*)  alloc((size_t)BB*NN*DL*2);
  u16*   q_bf   = (u16*)  alloc((size_t)BB*NN*DM*2);
  u16*   k_bf   = (u16*)  alloc((size_t)BB*NN*DM*2);
  u16*   v_bf   = (u16*)  alloc((size_t)BB*NN*DM*2);
  u16*   a_bf   = (u16*)  alloc((size_t)BB*NN*DM*2);
  u16*   s_bf   = (u16*)  alloc((size_t)BB*NN*NN*2);
  float* m_f    = (float*)alloc((size_t)BB*NN*4);
  int*   rankp  = (int*)  alloc((size_t)BB*16*NN*4);
  int*   mtop   = (int*)  alloc((size_t)BB*SK*4);
  int*   selmap = (int*)  alloc((size_t)BB*NN*4);
  float* vmean  = (float*)alloc((size_t)BB*DM*4);
  float* upd    = (float*)alloc((size_t)BB*SK*DM*4);
  u16*   wf2    = (u16*)  alloc((size_t)KTOT*NC*2);
  float* part   = (float*)alloc((size_t)BB*32*NC*4);

  // 1: pack weights + wf2 (no transpose)
  k_prep<<<dim3(1792), dim3(256), 0, stream>>>(Wlin, Wq, Wk, Wv, Wadd, wlinT, w4T, Wfin, wf2);
  // 2: x = emb @ Wlin + b  (BN=128 split, coalesced epilogue)
  k_gemm_x<<<dim3(256, 2), dim3(256), 0, stream>>>(emb, wlinT, blin, x_bf);
  // 3: Q,K,V,A (coalesced epilogue)
  k_gemm_qkva<<<dim3(128, 4), dim3(256), 0, stream>>>(x_bf, w4T, badd, q_bf, k_bf, v_bf, a_bf);
  // 4: S = Q K^T per batch -> bf16, coalesced epilogue
  k_gemm_s<<<dim3(8, 8, 16), dim3(256), 0, stream>>>(q_bf, k_bf, s_bf);
  // 5: M scores
  k_mscore<<<dim3(BB*NN/4), dim3(256), 0, stream>>>(s_bf, idxs, m_f);
  // 6: partial ranks + vmean
  k_rankvm<<<dim3(272), dim3(256), 0, stream>>>(m_f, rankp, v_bf, vmean);
  // 7: select top-140
  k_sel<<<dim3(BB), dim3(1024), 0, stream>>>(rankp, mtop, selmap);
  // 8: attention rows -> compact upd (coalesced PV)
  k_attn<<<dim3(SK/4, BB), dim3(256), 0, stream>>>(s_bf, v_bf, mtop, upd);
  // 9/10: final projection
  k_final<<<dim3(BB, 32), dim3(256), 0, stream>>>(upd, vmean, selmap, a_bf, wf2, part);
  k_out<<<dim3(1), dim3(256), 0, stream>>>(part, bfin, out);
}

// Round 14
// 104.588 us; speedup vs baseline: 1.2141x; 1.0822x over previous
//
#include <hip/hip_runtime.h>

typedef __attribute__((ext_vector_type(8))) short short8;
typedef __attribute__((ext_vector_type(4))) float f32x4;
typedef unsigned short u16;
typedef unsigned int u32;
typedef __attribute__((address_space(1))) const u32 gu32;
typedef __attribute__((address_space(3))) u32 lu32;

// ---------- bf16 helpers ----------
__device__ __forceinline__ u16 f2bf(float f){
  unsigned u = __float_as_uint(f);
  u += 0x7FFF + ((u >> 16) & 1);          // round-to-nearest-even
  return (u16)(u >> 16);
}
__device__ __forceinline__ float bf2f(u16 h){ return __uint_as_float(((unsigned)h) << 16); }

// ---------- problem constants ----------
#define BB   16
#define NN   1024
#define DML  512
#define DL   256
#define DM   128
#define NC   10
#define SK   140
#define KTOT (NN*DM)          // 131072

// ---------- K_prep: pack weights bf16-transposed | convert W_final -> bf16 [k][c] ----------
__global__ void k_prep(const float* __restrict__ Wlin, const float* __restrict__ Wq,
                       const float* __restrict__ Wk, const float* __restrict__ Wv,
                       const float* __restrict__ Wadd,
                       u16* __restrict__ wlinT, u16* __restrict__ w4T,
                       const float* __restrict__ Wf, u16* __restrict__ wf2){
  int blk = blockIdx.x, t = threadIdx.x;
  if (blk < 512){
    int id = blk*256 + t;              // 131072
    {
      int j = id >> 9;        // 0..255  (DL)
      int k = id & 511;       // 0..511  (DML)
      wlinT[id] = f2bf(Wlin[k*DL + j]);
    }
    {
      int j = id >> 8;        // 0..511  (4*DM)
      int k = id & 255;       // 0..255  (DL)
      const float* src = (j < 128) ? Wq : (j < 256) ? Wk : (j < 384) ? Wv : Wadd;
      int jj = j & 127;
      w4T[id] = f2bf(src[k*DM + jj]);
    }
  } else {
    // W_final is already [k][c] row-major: pure f32->bf16 convert, vectorized
    int i4 = (blk-512)*256 + t;        // 327,680 float4s  (1,310,720 elems)
    float4 v = ((const float4*)Wf)[i4];
    ushort4 o; o.x=f2bf(v.x); o.y=f2bf(v.y); o.z=f2bf(v.z); o.w=f2bf(v.w);
    ((ushort4*)wf2)[i4] = o;
  }
}

// ---------- GEMM staging helpers (128-row tiles, BK=64) ----------
__device__ __forceinline__ void stage2(const u16* __restrict__ A, const u16* __restrict__ B,
                                       int K, int m0, int n0, int kb,
                                       u16* sA, u16* sB, int tid, int wave){
  #pragma unroll
  for (int i = 0; i < 4; ++i){
    int ci  = i*256 + tid;
    int row = ci >> 3;
    int kc  = (ci & 7) ^ (row & 7);
    __builtin_amdgcn_global_load_lds((gu32*)(A + (long)(m0+row)*K + kb + kc*8),
                                     (lu32*)(sA + (i*256 + wave*64)*8), 16, 0, 0);
    __builtin_amdgcn_global_load_lds((gu32*)(B + (long)(n0+row)*K + kb + kc*8),
                                     (lu32*)(sB + (i*256 + wave*64)*8), 16, 0, 0);
  }
}
// MFMA over one 64-wide K tile (128x128 tile, 4 waves of 64x64)
__device__ __forceinline__ void compute64(const u16* sA, const u16* sB,
                                          int lane, int wrow, int wcol, f32x4 acc[4][4]){
  #pragma unroll
  for (int kk = 0; kk < 2; ++kk){
    short8 af[4], bfr[4];
    int cb = kk*4 + (lane >> 4);
    #pragma unroll
    for (int m_=0; m_<4; ++m_){
      int row = wrow + m_*16 + (lane & 15);
      af[m_] = *(const short8*)&sA[row*64 + ((cb ^ (row & 7)) << 3)];
    }
    #pragma unroll
    for (int n_=0; n_<4; ++n_){
      int row = wcol + n_*16 + (lane & 15);
      bfr[n_] = *(const short8*)&sB[row*64 + ((cb ^ (row & 7)) << 3)];
    }
    #pragma unroll
    for (int m_=0; m_<4; ++m_)
      #pragma unroll
      for (int n_=0; n_<4; ++n_)
        acc[m_][n_] = __builtin_amdgcn_mfma_f32_16x16x32_bf16(af[m_], bfr[n_], acc[m_][n_], 0, 0, 0);
  }
}
// double-buffered core: 1 barrier per K-step, stage(next) overlaps compute(cur)
__device__ __forceinline__ void gemm_core_db(const u16* __restrict__ A, const u16* __restrict__ B,
                                             int K, int m0, int n0,
                                             u16* sA0, u16* sB0, u16* sA1, u16* sB1,
                                             f32x4 acc[4][4]){
  const int tid  = threadIdx.x;
  const int lane = tid & 63;
  const int wave = tid >> 6;
  const int wrow = (wave >> 1) * 64;
  const int wcol = (wave & 1) * 64;
  u16 *cA = sA0, *cB = sB0, *nA = sA1, *nB = sB1;
  stage2(A, B, K, m0, n0, 0, cA, cB, tid, wave);
  __syncthreads();
  int nt = K >> 6;
  for (int t = 0; t < nt-1; ++t){
    stage2(A, B, K, m0, n0, (t+1)*64, nA, nB, tid, wave);
    compute64(cA, cB, lane, wrow, wcol, acc);
    __syncthreads();
    u16* x;
    x = cA; cA = nA; nA = x;
    x = cB; cB = nB; nB = x;
  }
  compute64(cA, cB, lane, wrow, wcol, acc);
}

// ---------- K2: x = emb(f32) @ W_lin + b_lin -> bf16 ; BM=64 x BN=128, coalesced epilogue ----------
__global__ __launch_bounds__(256) void k_gemm_x(const float* __restrict__ A, const u16* __restrict__ B,
                                                const float* __restrict__ bias, u16* __restrict__ out){
  __shared__ u16 smem[12288];   // 24KB: sA = [0,4096), sB = [4096,12288)
  u16* sA = smem;
  u16* sB = smem + 4096;
  const int tid  = threadIdx.x;
  const int lane = tid & 63;
  const int wave = tid >> 6;
  const int wrow = (wave >> 1) * 32;
  const int wcol = (wave & 1) * 64;
  int m0 = blockIdx.x*64, n0 = blockIdx.y*128;
  f32x4 acc[2][4];
  f32x4 z = {0.f,0.f,0.f,0.f};
  #pragma unroll
  for (int m_=0;m_<2;++m_) for (int n_=0;n_<4;++n_) acc[m_][n_] = z;

  f32x4 ra[4];      // A: 16 f32 per thread (row = tid>>2, two chunks kc=aq*2, aq*2+1)
  short8 rb[4];     // B: 4 chunks per thread
  const int arow = tid >> 2, aq = tid & 3;

  // prologue: tile 0
  {
    const float* src = A + (long)(m0+arow)*DML + aq*16;
    ra[0] = ((const f32x4*)src)[0]; ra[1] = ((const f32x4*)src)[1];
    ra[2] = ((const f32x4*)src)[2]; ra[3] = ((const f32x4*)src)[3];
    #pragma unroll
    for (int i=0;i<4;++i){
      int ci = i*256 + tid, row = ci>>3, kc = ci&7;
      rb[i] = *(const short8*)(B + (long)(n0+row)*DML + kc*8);
    }
  }
  {
    short8 o0, o1;
    #pragma unroll
    for (int j=0;j<4;++j){ o0[j]=(short)f2bf(ra[0][j]); o0[4+j]=(short)f2bf(ra[1][j]);
                           o1[j]=(short)f2bf(ra[2][j]); o1[4+j]=(short)f2bf(ra[3][j]); }
    int kc0 = aq*2, kc1 = aq*2+1;
    *(short8*)&sA[arow*64 + ((kc0 ^ (arow&7))<<3)] = o0;
    *(short8*)&sA[arow*64 + ((kc1 ^ (arow&7))<<3)] = o1;
    #pragma unroll
    for (int i=0;i<4;++i){
      int ci = i*256 + tid, row = ci>>3, kc = ci&7;
      *(short8*)&sB[row*64 + ((kc ^ (row&7))<<3)] = rb[i];
    }
  }
  __syncthreads();

  for (int tt = 0; tt < 8; ++tt){
    if (tt < 7){
      int kb = (tt+1)*64;
      const float* src = A + (long)(m0+arow)*DML + kb + aq*16;
      ra[0] = ((const f32x4*)src)[0]; ra[1] = ((const f32x4*)src)[1];
      ra[2] = ((const f32x4*)src)[2]; ra[3] = ((const f32x4*)src)[3];
      #pragma unroll
      for (int i=0;i<4;++i){
        int ci = i*256 + tid, row = ci>>3, kc = ci&7;
        rb[i] = *(const short8*)(B + (long)(n0+row)*DML + kb + kc*8);
      }
    }
    #pragma unroll
    for (int kk = 0; kk < 2; ++kk){
      short8 af[2], bfr[4];
      int cb = kk*4 + (lane >> 4);
      #pragma unroll
      for (int m_=0; m_<2; ++m_){
        int row = wrow + m_*16 + (lane & 15);
        af[m_] = *(const short8*)&sA[row*64 + ((cb ^ (row & 7)) << 3)];
      }
      #pragma unroll
      for (int n_=0; n_<4; ++n_){
        int row = wcol + n_*16 + (lane & 15);
        bfr[n_] = *(const short8*)&sB[row*64 + ((cb ^ (row & 7)) << 3)];
      }
      #pragma unroll
      for (int m_=0; m_<2; ++m_)
        #pragma unroll
        for (int n_=0; n_<4; ++n_)
          acc[m_][n_] = __builtin_amdgcn_mfma_f32_16x16x32_bf16(af[m_], bfr[n_], acc[m_][n_], 0, 0, 0);
    }
    __syncthreads();                 // after tt=7 this guarantees all waves done reading sB
    if (tt < 7){
      short8 o0, o1;
      #pragma unroll
      for (int j=0;j<4;++j){ o0[j]=(short)f2bf(ra[0][j]); o0[4+j]=(short)f2bf(ra[1][j]);
                             o1[j]=(short)f2bf(ra[2][j]); o1[4+j]=(short)f2bf(ra[3][j]); }
      int kc0 = aq*2, kc1 = aq*2+1;
      *(short8*)&sA[arow*64 + ((kc0 ^ (arow&7))<<3)] = o0;
      *(short8*)&sA[arow*64 + ((kc1 ^ (arow&7))<<3)] = o1;
      #pragma unroll
      for (int i=0;i<4;++i){
        int ci = i*256 + tid, row = ci>>3, kc = ci&7;
        *(short8*)&sB[row*64 + ((kc ^ (row&7))<<3)] = rb[i];
      }
      __syncthreads();
    }
  }

  // C tile -> LDS (sB region, 64x128 bf16 = 16KB), then coalesced store
  u16* sC = sB;
  #pragma unroll
  for (int m_=0;m_<2;++m_)
    #pragma unroll
    for (int n_=0;n_<4;++n_)
      #pragma unroll
      for (int rr=0;rr<4;++rr){
        int row = wrow + m_*16 + (lane>>4)*4 + rr;
        int col = wcol + n_*16 + (lane & 15);
        sC[row*128 + col] = f2bf(acc[m_][n_][rr] + bias[n0 + col]);
      }
  __syncthreads();
  #pragma unroll
  for (int i = 0; i < 4; ++i){
    int ci = i*256 + tid;
    int row = ci >> 4, c = ci & 15;
    *(short8*)(out + (long)(m0+row)*DL + n0 + c*8) = *(const short8*)&sC[row*128 + c*8];
  }
}

// ---------- K3: [Q|K|V|A] = x @ [Wq|Wk|Wv|Wadd], coalesced epilogue ----------
__global__ __launch_bounds__(256) void k_gemm_qkva(const u16* __restrict__ A, const u16* __restrict__ B,
                                                   const float* __restrict__ badd,
                                                   u16* __restrict__ oq, u16* __restrict__ ok,
                                                   u16* __restrict__ ov, u16* __restrict__ oa){
  __shared__ u16 smem[32768];   // 64KB; nt=4 even -> final compute reads smem[16384..), so [0,16384) free for C
  f32x4 acc[4][4];
  f32x4 z = {0.f,0.f,0.f,0.f};
  #pragma unroll
  for (int m_=0;m_<4;++m_) for (int n_=0;n_<4;++n_) acc[m_][n_] = z;
  int m0 = blockIdx.x*128;
  int tn = blockIdx.y;              // 0=Q 1=K 2=V 3=A
  gemm_core_db(A, B, DL, m0, tn*128, smem, smem+8192, smem+16384, smem+24576, acc);
  int tid = threadIdx.x, lane = tid & 63, wave = tid >> 6;
  int wrow = (wave>>1)*64, wcol = (wave&1)*64;
  u16* dst = (tn==0) ? oq : (tn==1) ? ok : (tn==2) ? ov : oa;

  u16* sC = smem;                   // [128][128] bf16
  #pragma unroll
  for (int m_=0;m_<4;++m_)
    #pragma unroll
    for (int n_=0;n_<4;++n_)
      #pragma unroll
      for (int r=0;r<4;++r){
        int row = wrow + m_*16 + (lane>>4)*4 + r;
        int col = wcol + n_*16 + (lane & 15);
        float v = acc[m_][n_][r];
        if (tn == 3) v += badd[col];
        sC[row*128 + col] = f2bf(v);
      }
  __syncthreads();
  u16* db = dst + (long)m0*DM;
  #pragma unroll
  for (int i = 0; i < 8; ++i){
    int ci = i*256 + tid;
    int row = ci >> 4, c = ci & 15;
    *(short8*)(db + (long)row*DM + c*8) = *(const short8*)&sC[row*128 + c*8];
  }
}

// ---------- K4: S[b] = Q[b] @ K[b]^T -> bf16 ----------
// 32KB LDS (single-buffer BK=64) -> 5 blocks/CU for latency hiding; grid b-fastest (XCD pin)
__global__ __launch_bounds__(256) void k_gemm_s(const u16* __restrict__ Q, const u16* __restrict__ Km,
                                                u16* __restrict__ S){
  __shared__ u16 smem[16384];     // 32KB: sA [0,8192), sB [8192,16384); reused for C tile
  u16* sA = smem;
  u16* sB = smem + 8192;
  const int tid = threadIdx.x, lane = tid & 63, wave = tid >> 6;
  const int wrow = (wave>>1)*64, wcol = (wave&1)*64;
  f32x4 acc[4][4];
  f32x4 z = {0.f,0.f,0.f,0.f};
  #pragma unroll
  for (int m_=0;m_<4;++m_) for (int n_=0;n_<4;++n_) acc[m_][n_] = z;
  int b = blockIdx.x, n0 = blockIdx.y*128, m0 = blockIdx.z*128;   // b fastest => batch pinned to XCD b%8
  const u16* A = Q  + (long)b*NN*DM;
  const u16* B = Km + (long)b*NN*DM;

  stage2(A, B, DM, m0, n0, 0, sA, sB, tid, wave);
  __syncthreads();
  compute64(sA, sB, lane, wrow, wcol, acc);
  __syncthreads();
  stage2(A, B, DM, m0, n0, 64, sA, sB, tid, wave);
  __syncthreads();
  compute64(sA, sB, lane, wrow, wcol, acc);
  __syncthreads();

  // C tile -> LDS (32KB = exactly 128x128 bf16), then coalesced store
  u16* sS = smem;
  #pragma unroll
  for (int m_=0;m_<4;++m_)
    #pragma unroll
    for (int n_=0;n_<4;++n_)
      #pragma unroll
      for (int r=0;r<4;++r){
        int row = wrow + m_*16 + (lane>>4)*4 + r;
        int col = wcol + n_*16 + (lane & 15);
        sS[row*128 + col] = f2bf(acc[m_][n_][r]);
      }
  __syncthreads();

  u16* Sb = S + (long)b*NN*NN + (long)m0*NN + n0;
  #pragma unroll
  for (int i = 0; i < 8; ++i){
    int ci = i*256 + tid;
    int row = ci >> 4, c = ci & 15;
    *(short8*)(Sb + (long)row*NN + c*8) = *(const short8*)&sS[row*128 + c*8];
  }
}

// ---------- K5: M[b,l] = max_s S[b,l,idx[l,s]] - sum_s(...)/1024 ; grid (b, lblk) ----------
__global__ void k_mscore(const u16* __restrict__ S, const int* __restrict__ idx, float* __restrict__ M){
  int b = blockIdx.x;                              // fastest => XCD pin
  int l = blockIdx.y*4 + (threadIdx.x >> 6);
  int lane = threadIdx.x & 63;
  const u16* Srow = S + (long)b*NN*NN + (long)l*NN;
  const int* ir = idx + l*SK;
  float mx = -1e30f, sm = 0.f;
  for (int s = lane; s < SK; s += 64){
    float v = bf2f(Srow[ir[s]]);
    mx = fmaxf(mx, v); sm += v;
  }
  #pragma unroll
  for (int o=32;o;o>>=1){ mx = fmaxf(mx, __shfl_xor(mx,o)); sm += __shfl_xor(sm,o); }
  if (lane == 0) M[b*NN + l] = mx - sm * (1.0f/1024.0f);
}

// ---------- K6a: partial ranks (blocks 0..255) + V column-mean (blocks 256..271) ----------
__global__ __launch_bounds__(256) void k_rankvm(const float* __restrict__ M, int* __restrict__ partial,
                                                const u16* __restrict__ V, float* __restrict__ vmean){
  __shared__ float sC[64];
  __shared__ float red[16][128];
  int blk = blockIdx.x, t = threadIdx.x;
  if (blk < 256){
    int jc = blk & 15, b = blk >> 4;
    const float* Mb = M + b*NN;
    if (t < 64) sC[t] = Mb[jc*64 + t];
    __syncthreads();
    int j0 = jc*64;
    float mi[4];
    int cnt[4] = {0,0,0,0};
    #pragma unroll
    for (int r=0;r<4;++r) mi[r] = Mb[t + r*256];
    for (int j = 0; j < 64; ++j){
      float mj = sC[j];
      int jg = j0 + j;
      #pragma unroll
      for (int r=0;r<4;++r){
        int i = t + r*256;
        cnt[r] += (mj > mi[r]) || (mj == mi[r] && jg < i);
      }
    }
    int* pb = partial + (b*16 + jc)*NN;
    #pragma unroll
    for (int r=0;r<4;++r) pb[t + r*256] = cnt[r];
  } else {
    int b = blk - 256;
    int d8 = t & 15, seg = t >> 4;
    const u16* Vb = V + (long)b*KTOT + seg*64*DM + d8*8;
    float acc[8] = {0,0,0,0,0,0,0,0};
    for (int l = 0; l < 64; ++l){
      short8 v = *(const short8*)(Vb + l*DM);
      #pragma unroll
      for (int j=0;j<8;++j) acc[j] += bf2f((u16)v[j]);
    }
    #pragma unroll
    for (int j=0;j<8;++j) red[seg][d8*8+j] = acc[j];
    __syncthreads();
    if (t < 128){
      float s = 0.f;
      #pragma unroll
      for (int g=0;g<16;++g) s += red[g][t];
      vmean[b*DM + t] = s * (1.0f/1024.0f);
    }
  }
}

// ---------- K6b: sum partial ranks -> mtop + selmap ----------
__global__ __launch_bounds__(1024) void k_sel(const int* __restrict__ partial, int* __restrict__ mtop,
                                              int* __restrict__ selmap){
  int b = blockIdx.x, i = threadIdx.x;
  int cnt = 0;
  #pragma unroll
  for (int jc = 0; jc < 16; ++jc) cnt += partial[(b*16 + jc)*NN + i];
  selmap[b*NN + i] = (cnt < SK) ? cnt : -1;
  if (cnt < SK) mtop[b*SK + cnt] = i;
}

// ---------- K9: softmax(S_row/sqrt(d)) @ V for top-140 rows, 4 rows/block ; grid (b, ublk) ----------
__global__ __launch_bounds__(256) void k_attn(const u16* __restrict__ S, const u16* __restrict__ V,
                                              const int* __restrict__ mtop, float* __restrict__ upd){
  __shared__ float sE[4][1024];
  __shared__ float redM[4][4];
  __shared__ float redS[4][4];
  __shared__ float sP[4][4][128];   // [wave][row][d] 8KB
  int b = blockIdx.x, u0 = blockIdx.y*4, t = threadIdx.x;   // b fastest => XCD pin
  int lane = t & 63, wave = t >> 6;
  const float inv = 0.08838834764831845f;   // 1/sqrt(128)

  int rows[4];
  #pragma unroll
  for (int r=0;r<4;++r) rows[r] = mtop[b*SK + u0 + r];

  float sv[4][4];
  float pm[4];
  const u16* Sb = S + (long)b*NN*NN;
  #pragma unroll
  for (int r=0;r<4;++r){
    ushort4 raw = ((const ushort4*)(Sb + (long)rows[r]*NN))[t];
    sv[r][0] = bf2f(raw.x)*inv; sv[r][1] = bf2f(raw.y)*inv;
    sv[r][2] = bf2f(raw.z)*inv; sv[r][3] = bf2f(raw.w)*inv;
    pm[r] = fmaxf(fmaxf(sv[r][0],sv[r][1]), fmaxf(sv[r][2],sv[r][3]));
  }
  #pragma unroll
  for (int o=32;o;o>>=1)
    #pragma unroll
    for (int r=0;r<4;++r) pm[r] = fmaxf(pm[r], __shfl_xor(pm[r],o));
  if (lane == 0){
    #pragma unroll
    for (int r=0;r<4;++r) redM[wave][r] = pm[r];
  }
  __syncthreads();
  float mx[4], ps[4];
  #pragma unroll
  for (int r=0;r<4;++r)
    mx[r] = fmaxf(fmaxf(redM[0][r],redM[1][r]), fmaxf(redM[2][r],redM[3][r]));
  #pragma unroll
  for (int r=0;r<4;++r){
    float s = 0.f;
    #pragma unroll
    for (int j=0;j<4;++j){
      float e = __expf(sv[r][j] - mx[r]);
      sE[r][t*4+j] = e;
      s += e;
    }
    ps[r] = s;
  }
  #pragma unroll
  for (int o=32;o;o>>=1)
    #pragma unroll
    for (int r=0;r<4;++r) ps[r] += __shfl_xor(ps[r],o);
  if (lane == 0){
    #pragma unroll
    for (int r=0;r<4;++r) redS[wave][r] = ps[r];
  }
  __syncthreads();
  float rZ[4];
  #pragma unroll
  for (int r=0;r<4;++r)
    rZ[r] = 1.0f / (redS[0][r]+redS[1][r]+redS[2][r]+redS[3][r]);

  // ---- PV, coalesced: dg = t&15, kg = t>>4 ----
  int dg = t & 15;
  int kg = t >> 4;
  const u16* Vb = V + (long)b*KTOT + dg*8;
  float acc[4][8];
  #pragma unroll
  for (int r=0;r<4;++r)
    #pragma unroll
    for (int j=0;j<8;++j) acc[r][j] = 0.f;

  for (int k = kg; k < NN; k += 16){
    short8 v = *(const short8*)(Vb + (long)k*DM);
    float vf[8];
    #pragma unroll
    for (int j=0;j<8;++j) vf[j] = bf2f((u16)v[j]);
    #pragma unroll
    for (int r=0;r<4;++r){
      float e = sE[r][k];
      #pragma unroll
      for (int j=0;j<8;++j) acc[r][j] += e * vf[j];
    }
  }

  // reduce over this wave's 4 kg values (lane bits 4,5)
  #pragma unroll
  for (int o=16;o<64;o<<=1)
    #pragma unroll
    for (int r=0;r<4;++r)
      #pragma unroll
      for (int j=0;j<8;++j) acc[r][j] += __shfl_xor(acc[r][j], o);

  if ((t & 63) < 16){
    #pragma unroll
    for (int r=0;r<4;++r)
      #pragma unroll
      for (int j=0;j<8;++j) sP[wave][r][dg*8+j] = acc[r][j];
  }
  __syncthreads();
  if (t < 128){
    #pragma unroll
    for (int r=0;r<4;++r){
      float s = sP[0][r][t] + sP[1][r][t] + sP[2][r][t] + sP[3][r][t];
      upd[((long)b*SK + u0 + r)*DM + t] = s * rZ[r];
    }
  }
}

// ---------- K11: final GEMV partials: (ctx+A) @ W_final ; wf2 is [k][c] contiguous ----------
__global__ __launch_bounds__(256) void k_final(const float* __restrict__ upd, const float* __restrict__ vmean,
                                               const int* __restrict__ selmap,
                                               const u16* __restrict__ Aad,
                                               const u16* __restrict__ wf2, float* __restrict__ part){
  int b = blockIdx.x, ch = blockIdx.y, t = threadIdx.x;
  long base = (long)b * KTOT;
  int k0 = ch * 4096;
  float acc[NC] = {0.f};
  for (int k = k0 + t; k < k0 + 4096; k += 256){
    int l = k >> 7, d = k & 127;
    int sel = selmap[b*NN + l];
    float c = (sel >= 0) ? upd[((long)b*SK + sel)*DM + d] : vmean[b*DM + d];
    float v = c + bf2f(Aad[base + k]);
    const u32* w32 = (const u32*)(wf2 + (long)k*NC);   // 10 bf16 = 20B contiguous
    #pragma unroll
    for (int cc = 0; cc < 5; ++cc){
      u32 w = w32[cc];
      acc[2*cc]   += v * bf2f((u16)(w & 0xFFFF));
      acc[2*cc+1] += v * bf2f((u16)(w >> 16));
    }
  }
  __shared__ float lred[40];
  int lane = t & 63, wave = t >> 6;
  #pragma unroll
  for (int c = 0; c < NC; ++c){
    float v = acc[c];
    #pragma unroll
    for (int o=32;o;o>>=1) v += __shfl_xor(v,o);
    if (lane == 0) lred[wave*NC + c] = v;
  }
  __syncthreads();
  if (t < NC) part[(b*32 + ch)*NC + t] = lred[t] + lred[NC+t] + lred[2*NC+t] + lred[3*NC+t];
}

// ---------- K12: reduce partials + bias -> out ----------
__global__ void k_out(const float* __restrict__ part, const float* __restrict__ bfin, float* __restrict__ out){
  int t = threadIdx.x;
  if (t < BB*NC){
    int b = t / NC, c = t % NC;
    float s = bfin[c];
    #pragma unroll
    for (int ch = 0; ch < 32; ++ch) s += part[(b*32 + ch)*NC + c];
    out[t] = s;
  }
}

// ---------- launch ----------
extern "C" void kernel_launch(void* const* d_in, const int* in_sizes, int n_in,
                              void* d_out, int out_size, void* d_ws, size_t ws_size,
                              hipStream_t stream){
  const float* emb  = (const float*)d_in[0];
  const int*   idxs = (const int*)  d_in[1];
  const float* Wlin = (const float*)d_in[2];
  const float* blin = (const float*)d_in[3];
  const float* Wq   = (const float*)d_in[4];
  const float* Wk   = (const float*)d_in[5];
  const float* Wv   = (const float*)d_in[6];
  const float* Wadd = (const float*)d_in[7];
  const float* badd = (const float*)d_in[8];
  const float* Wfin = (const float*)d_in[9];
  const float* bfin = (const float*)d_in[10];
  float* out = (float*)d_out;

  char* p = (char*)d_ws;
  auto alloc = [&](size_t bytes)->char*{ char* r = p; p += (bytes + 255) & ~(size_t)255; return r; };
  u16*   wlinT  = (u16*)  alloc((size_t)DL*DML*2);
  u16*   w4T    = (u16*)  alloc((size_t)4*DM*DL*2);
  u16*   x_bf   = (u16*)  alloc((size_t)BB*NN*DL*2);
  u16*   q_bf   = (u16*)  alloc((size_t)BB*NN*DM*2);
  u16*   k_bf   = (u16*)  alloc((size_t)BB*NN*DM*2);
  u16*   v_bf   = (u16*)  alloc((size_t)BB*NN*DM*2);
  u16*   a_bf   = (u16*)  alloc((size_t)BB*NN*DM*2);
  u16*   s_bf   = (u16*)  alloc((size_t)BB*NN*NN*2);
  float* m_f    = (float*)alloc((size_t)BB*NN*4);
  int*   rankp  = (int*)  alloc((size_t)BB*16*NN*4);
  int*   mtop   = (int*)  alloc((size_t)BB*SK*4);
  int*   selmap = (int*)  alloc((size_t)BB*NN*4);
  float* vmean  = (float*)alloc((size_t)BB*DM*4);
  float* upd    = (float*)alloc((size_t)BB*SK*DM*4);
  u16*   wf2    = (u16*)  alloc((size_t)KTOT*NC*2);
  float* part   = (float*)alloc((size_t)BB*32*NC*4);

  // 1: pack weights + wf2 (no transpose)
  k_prep<<<dim3(1792), dim3(256), 0, stream>>>(Wlin, Wq, Wk, Wv, Wadd, wlinT, w4T, Wfin, wf2);
  // 2: x = emb @ Wlin + b  (BN=128 split, coalesced epilogue)
  k_gemm_x<<<dim3(256, 2), dim3(256), 0, stream>>>(emb, wlinT, blin, x_bf);
  // 3: Q,K,V,A (coalesced epilogue)
  k_gemm_qkva<<<dim3(128, 4), dim3(256), 0, stream>>>(x_bf, w4T, badd, q_bf, k_bf, v_bf, a_bf);
  // 4: S = Q K^T per batch -> bf16 (32KB LDS, 5 blocks/CU; b-fastest grid)
  k_gemm_s<<<dim3(16, 8, 8), dim3(256), 0, stream>>>(q_bf, k_bf, s_bf);
  // 5: M scores (b-fastest grid)
  k_mscore<<<dim3(BB, NN/4), dim3(256), 0, stream>>>(s_bf, idxs, m_f);
  // 6: partial ranks + vmean
  k_rankvm<<<dim3(272), dim3(256), 0, stream>>>(m_f, rankp, v_bf, vmean);
  // 7: select top-140
  k_sel<<<dim3(BB), dim3(1024), 0, stream>>>(rankp, mtop, selmap);
  // 8: attention rows -> compact upd (b-fastest grid)
  k_attn<<<dim3(BB, SK/4), dim3(256), 0, stream>>>(s_bf, v_bf, mtop, upd);
  // 9/10: final projection
  k_final<<<dim3(BB, 32), dim3(256), 0, stream>>>(upd, vmean, selmap, a_bf, wf2, part);
  k_out<<<dim3(1), dim3(256), 0, stream>>>(part, bfin, out);
}